// Round 1
// baseline (1084.596 us; speedup 1.0000x reference)
//
#include <hip/hip_runtime.h>
#include <math.h>

// ---------------- helpers ----------------
static __device__ __forceinline__ float lrelu(float x) { return x > 0.0f ? x : 0.2f * x; }

// monotone float<->uint mapping for atomicMax on floats
static __device__ __forceinline__ unsigned ordf(float f) {
    int i = __float_as_int(f);
    return (unsigned)(i ^ ((i >> 31) | 0x80000000));
}
static __device__ __forceinline__ float unordf(unsigned u) {
    int i = (u & 0x80000000u) ? (int)(u ^ 0x80000000u) : (int)(~u);
    return __int_as_float(i);
}

// consts layout (floats):
// [0] sum_ea (atomic), [1] c_edge, [2..6] va, [7..11] vd, [16..143] bc, [144..783] Wc[5][128]

// ---------------- setup: fold weights ----------------
__global__ void k_setup(const float* __restrict__ W_gat, const float* __restrict__ att_src,
                        const float* __restrict__ att_dst, const float* __restrict__ W_edge,
                        const float* __restrict__ att_edge, const float* __restrict__ b_gat,
                        const float* __restrict__ W_fc1, const float* __restrict__ b_fc1,
                        float* __restrict__ consts) {
    int t = threadIdx.x;  // 128 threads
    if (t == 0) {
        float c = 0.f;
        for (int k = 0; k < 64; k++) c += W_edge[k] * att_edge[k];
        consts[1] = c;
    }
    if (t < 5) {
        float a = 0.f, b = 0.f;
        for (int c = 0; c < 64; c++) {
            float w = W_gat[t * 64 + c];
            a += w * att_src[c];
            b += w * att_dst[c];
        }
        consts[2 + t] = a;
        consts[7 + t] = b;
    }
    float bcv = b_fc1[t];
    for (int c = 0; c < 64; c++) bcv += b_gat[c] * W_fc1[c * 128 + t];
    consts[16 + t] = bcv;
    for (int k = 0; k < 5; k++) {
        float w = 0.f;
        for (int c = 0; c < 64; c++) w += W_gat[k * 64 + c] * W_fc1[c * 128 + t];
        consts[144 + k * 128 + t] = w;
    }
}

// ---------------- sum(edge_attr) ----------------
__global__ void k_easum(const float* __restrict__ ea, float* __restrict__ consts, int n) {
    __shared__ float s[256];
    int i = blockIdx.x * blockDim.x + threadIdx.x;
    float v = (i < n) ? ea[i] : 0.f;
    s[threadIdx.x] = v;
    __syncthreads();
    for (int o = 128; o > 0; o >>= 1) {
        if (threadIdx.x < o) s[threadIdx.x] += s[threadIdx.x + o];
        __syncthreads();
    }
    if (threadIdx.x == 0) atomicAdd(&consts[0], s[0]);
}

// ---------------- per-node: a_s, a_d, init max with self-loop alpha ----------------
__global__ void k_nodes(const float* __restrict__ x, const float* __restrict__ consts,
                        float* __restrict__ a_s, float* __restrict__ a_d,
                        unsigned* __restrict__ m_u, int n, float inv_E) {
    int i = blockIdx.x * blockDim.x + threadIdx.x;
    if (i >= n) return;
    const float* xi = x + (size_t)i * 5;
    float x0 = xi[0], x1 = xi[1], x2 = xi[2], x3 = xi[3], x4 = xi[4];
    float as = x0 * consts[2] + x1 * consts[3] + x2 * consts[4] + x3 * consts[5] + x4 * consts[6];
    float ad = x0 * consts[7] + x1 * consts[8] + x2 * consts[9] + x3 * consts[10] + x4 * consts[11];
    a_s[i] = as;
    a_d[i] = ad;
    float mean_ea = consts[0] * inv_E;
    float aself = lrelu(as + ad + consts[1] * mean_ea);
    m_u[i] = ordf(aself);
}

// ---------------- edge pass 1: alpha + segment max ----------------
__global__ void k_edge1(const int* __restrict__ src, const int* __restrict__ dst,
                        const float* __restrict__ ea, const float* __restrict__ a_s,
                        const float* __restrict__ a_d, const float* __restrict__ consts,
                        float* __restrict__ alpha, unsigned* __restrict__ m_u, int n) {
    int e = blockIdx.x * blockDim.x + threadIdx.x;
    if (e >= n) return;
    int s = src[e], d = dst[e];
    float al = lrelu(a_s[s] + a_d[d] + consts[1] * ea[e]);
    alpha[e] = al;
    atomicMax(&m_u[d], ordf(al));
}

// ---------------- per-node: decode max, init denom with self exp ----------------
__global__ void k_node2(const float* __restrict__ a_s, const float* __restrict__ a_d,
                        const float* __restrict__ consts, float* __restrict__ m_f,
                        float* __restrict__ s_sum, int n, float inv_E) {
    int i = blockIdx.x * blockDim.x + threadIdx.x;
    if (i >= n) return;
    unsigned u = __float_as_uint(m_f[i]);
    float m = unordf(u);
    float mean_ea = consts[0] * inv_E;
    float aself = lrelu(a_s[i] + a_d[i] + consts[1] * mean_ea);
    s_sum[i] = __expf(aself - m);
    m_f[i] = m;
}

// ---------------- edge pass 2: exp + segment sum ----------------
__global__ void k_edge2(const int* __restrict__ dst, const float* __restrict__ m_f,
                        float* __restrict__ alpha_ex, float* __restrict__ s_sum, int n) {
    int e = blockIdx.x * blockDim.x + threadIdx.x;
    if (e >= n) return;
    int d = dst[e];
    float ex = __expf(alpha_ex[e] - m_f[d]);
    alpha_ex[e] = ex;
    atomicAdd(&s_sum[d], ex);
}

// ---------------- edge pass 3: weighted x scatter ----------------
__global__ void k_edge3(const int* __restrict__ src, const int* __restrict__ dst,
                        const float* __restrict__ alpha_ex, const float* __restrict__ s_sum,
                        const float* __restrict__ x, float* __restrict__ xagg, int n) {
    int e = blockIdx.x * blockDim.x + threadIdx.x;
    if (e >= n) return;
    int s = src[e], d = dst[e];
    float w = alpha_ex[e] / (s_sum[d] + 1e-16f);
    const float* xs = x + (size_t)s * 5;
    float* xd = xagg + (size_t)d * 5;
    atomicAdd(&xd[0], w * xs[0]);
    atomicAdd(&xd[1], w * xs[1]);
    atomicAdd(&xd[2], w * xs[2]);
    atomicAdd(&xd[3], w * xs[3]);
    atomicAdd(&xd[4], w * xs[4]);
}

// ---------------- per-(node,channel): fused fc1 + relu + mean-pool accumulate ----------------
__global__ void k_node3(const float* __restrict__ x, const float* __restrict__ consts,
                        const float* __restrict__ a_s, const float* __restrict__ a_d,
                        const float* __restrict__ m_f, const float* __restrict__ s_sum,
                        const float* __restrict__ xagg, const int* __restrict__ pool_batch,
                        float* __restrict__ g_sum, float* __restrict__ bcnt, int n, float inv_E) {
    int idx = blockIdx.x * blockDim.x + threadIdx.x;
    int node = idx >> 7;
    int l = idx & 127;
    if (node >= n) return;
    float mean_ea = consts[0] * inv_E;
    float aself = lrelu(a_s[node] + a_d[node] + consts[1] * mean_ea);
    float wself = __expf(aself - m_f[node]) / (s_sum[node] + 1e-16f);
    const float* xa = xagg + (size_t)node * 5;
    const float* xs = x + (size_t)node * 5;
    float h = consts[16 + l];
#pragma unroll
    for (int k = 0; k < 5; k++) {
        float v = xa[k] + wself * xs[k];
        h += v * consts[144 + k * 128 + l];
    }
    h = fmaxf(h, 0.f);
    int b = pool_batch[node];
    atomicAdd(&g_sum[b * 128 + l], h);
    if (l == 0) atomicAdd(&bcnt[b], 1.0f);
}

// ---------------- head MLP: one block per batch row ----------------
__global__ void k_head(const float* __restrict__ g_sum, const float* __restrict__ bcnt,
                       const float* __restrict__ agent_state, const float* __restrict__ W_fc2,
                       const float* __restrict__ b_fc2, const float* __restrict__ W_v1,
                       const float* __restrict__ b_v1, const float* __restrict__ W_v2,
                       const float* __restrict__ b_v2, const float* __restrict__ W_a1,
                       const float* __restrict__ b_a1, const float* __restrict__ W_a2,
                       const float* __restrict__ b_a2, float* __restrict__ out, int A) {
    __shared__ float z[192];
    __shared__ float v1s[128], a1s[128], red[128];
    __shared__ float advs[8];
    int b = blockIdx.x, t = threadIdx.x;  // 128 threads
    float cnt = bcnt[b];
    cnt = cnt < 1.f ? 1.f : cnt;
    z[t] = g_sum[b * 128 + t] / cnt;
    if (t < 64) {
        float a = b_fc2[t];
        const float* as_ = agent_state + b * 34;
        for (int k = 0; k < 34; k++) a += as_[k] * W_fc2[k * 64 + t];
        z[128 + t] = fmaxf(a, 0.f);
    }
    __syncthreads();
    float v = b_v1[t], a = b_a1[t];
    for (int j = 0; j < 192; j++) {
        float zj = z[j];
        v += zj * W_v1[j * 128 + t];
        a += zj * W_a1[j * 128 + t];
    }
    v1s[t] = fmaxf(v, 0.f);
    a1s[t] = fmaxf(a, 0.f);
    __syncthreads();
    red[t] = v1s[t] * W_v2[t];
    __syncthreads();
    for (int o = 64; o > 0; o >>= 1) {
        if (t < o) red[t] += red[t + o];
        __syncthreads();
    }
    float value = red[0] + b_v2[0];
    if (t < A) {
        float ad = b_a2[t];
        for (int j = 0; j < 128; j++) ad += a1s[j] * W_a2[j * A + t];
        advs[t] = ad;
    }
    __syncthreads();
    if (t == 0) {
        float m = 0.f;
        for (int j = 0; j < A; j++) m += advs[j];
        m *= (1.f / (float)A);
        for (int j = 0; j < A; j++) out[b * A + j] = value + advs[j] - m;
    }
}

extern "C" void kernel_launch(void* const* d_in, const int* in_sizes, int n_in,
                              void* d_out, int out_size, void* d_ws, size_t ws_size,
                              hipStream_t stream) {
    const float* x        = (const float*)d_in[0];
    const int* edge_index = (const int*)d_in[1];
    const float* ea       = (const float*)d_in[2];
    const float* agent    = (const float*)d_in[3];
    const int* pool_batch = (const int*)d_in[4];
    const float* W_gat    = (const float*)d_in[5];
    const float* att_src  = (const float*)d_in[6];
    const float* att_dst  = (const float*)d_in[7];
    const float* W_edge   = (const float*)d_in[8];
    const float* att_edge = (const float*)d_in[9];
    const float* b_gat    = (const float*)d_in[10];
    const float* W_fc1    = (const float*)d_in[11];
    const float* b_fc1    = (const float*)d_in[12];
    const float* W_fc2    = (const float*)d_in[13];
    const float* b_fc2    = (const float*)d_in[14];
    const float* W_v1     = (const float*)d_in[15];
    const float* b_v1     = (const float*)d_in[16];
    const float* W_v2     = (const float*)d_in[17];
    const float* b_v2     = (const float*)d_in[18];
    const float* W_a1     = (const float*)d_in[19];
    const float* b_a1     = (const float*)d_in[20];
    const float* W_a2     = (const float*)d_in[21];
    const float* b_a2     = (const float*)d_in[22];

    const int N = in_sizes[0] / 5;
    const int E = in_sizes[2];
    const int B = in_sizes[3] / 34;
    const int A = out_size / B;
    const float inv_E = 1.0f / (float)E;

    const int* src = edge_index;
    const int* dst = edge_index + E;

    // ---- ws layout (bytes), zero-region first ----
    char* ws = (char*)d_ws;
    size_t off = 0;
    auto take = [&](size_t bytes) {
        size_t o = off;
        off = (off + bytes + 255) & ~(size_t)255;
        return o;
    };
    size_t o_consts = take(4096);                    // zeroed
    size_t o_xagg   = take((size_t)N * 5 * 4);       // zeroed
    size_t o_gsum   = take((size_t)B * 128 * 4);     // zeroed
    size_t o_bcnt   = take((size_t)B * 4);           // zeroed
    size_t zero_bytes = off;
    size_t o_as   = take((size_t)N * 4);
    size_t o_ad   = take((size_t)N * 4);
    size_t o_m    = take((size_t)N * 4);
    size_t o_s    = take((size_t)N * 4);
    size_t o_aex  = take((size_t)E * 4);
    (void)ws_size;

    float* consts   = (float*)(ws + o_consts);
    float* xagg     = (float*)(ws + o_xagg);
    float* g_sum    = (float*)(ws + o_gsum);
    float* bcnt     = (float*)(ws + o_bcnt);
    float* a_s      = (float*)(ws + o_as);
    float* a_d      = (float*)(ws + o_ad);
    float* m_f      = (float*)(ws + o_m);
    float* s_sum    = (float*)(ws + o_s);
    float* alpha_ex = (float*)(ws + o_aex);

    hipMemsetAsync(d_ws, 0, zero_bytes, stream);

    k_setup<<<1, 128, 0, stream>>>(W_gat, att_src, att_dst, W_edge, att_edge, b_gat, W_fc1, b_fc1, consts);

    int ebl = (E + 255) / 256;
    int nbl = (N + 255) / 256;
    k_easum<<<ebl, 256, 0, stream>>>(ea, consts, E);
    k_nodes<<<nbl, 256, 0, stream>>>(x, consts, a_s, a_d, (unsigned*)m_f, N, inv_E);
    k_edge1<<<ebl, 256, 0, stream>>>(src, dst, ea, a_s, a_d, consts, alpha_ex, (unsigned*)m_f, E);
    k_node2<<<nbl, 256, 0, stream>>>(a_s, a_d, consts, m_f, s_sum, N, inv_E);
    k_edge2<<<ebl, 256, 0, stream>>>(dst, m_f, alpha_ex, s_sum, E);
    k_edge3<<<ebl, 256, 0, stream>>>(src, dst, alpha_ex, s_sum, x, xagg, E);
    int n3bl = (int)(((size_t)N * 128 + 255) / 256);
    k_node3<<<n3bl, 256, 0, stream>>>(x, consts, a_s, a_d, m_f, s_sum, xagg, pool_batch, g_sum, bcnt, N, inv_E);
    k_head<<<B, 128, 0, stream>>>(g_sum, bcnt, agent, W_fc2, b_fc2, W_v1, b_v1, W_v2, b_v2,
                                  W_a1, b_a1, W_a2, b_a2, (float*)d_out, A);
}

// Round 2
// 755.413 us; speedup vs baseline: 1.4358x; 1.4358x over previous
//
#include <hip/hip_runtime.h>
#include <math.h>

// ---------------- helpers ----------------
static __device__ __forceinline__ float lrelu(float x) { return x > 0.0f ? x : 0.2f * x; }

static __device__ __forceinline__ unsigned xcc_id() {
    unsigned x;
    asm volatile("s_getreg_b32 %0, hwreg(HW_REG_XCC_ID)" : "=s"(x));
    return x & 7u;
}

// XCD-local atomic add: workgroup scope -> no sc1 -> executes at the local TCC (L2).
// Only safe because each XCD writes exclusively its own copy of the accumulator.
static __device__ __forceinline__ void xcd_atomic_add(float* p, float v) {
    __hip_atomic_fetch_add(p, v, __ATOMIC_RELAXED, __HIP_MEMORY_SCOPE_WORKGROUP);
}

// consts layout (floats):
// [0] sum_ea (atomic), [1] c_edge, [2..6] va, [7..11] vd, [16..143] bc, [144..783] Wc[5][128]

// ---------------- setup: fold weights ----------------
__global__ void k_setup(const float* __restrict__ W_gat, const float* __restrict__ att_src,
                        const float* __restrict__ att_dst, const float* __restrict__ W_edge,
                        const float* __restrict__ att_edge, const float* __restrict__ b_gat,
                        const float* __restrict__ W_fc1, const float* __restrict__ b_fc1,
                        float* __restrict__ consts) {
    int t = threadIdx.x;  // 128 threads
    if (t == 0) {
        float c = 0.f;
        for (int k = 0; k < 64; k++) c += W_edge[k] * att_edge[k];
        consts[1] = c;
    }
    if (t < 5) {
        float a = 0.f, b = 0.f;
        for (int c = 0; c < 64; c++) {
            float w = W_gat[t * 64 + c];
            a += w * att_src[c];
            b += w * att_dst[c];
        }
        consts[2 + t] = a;
        consts[7 + t] = b;
    }
    float bcv = b_fc1[t];
    for (int c = 0; c < 64; c++) bcv += b_gat[c] * W_fc1[c * 128 + t];
    consts[16 + t] = bcv;
    for (int k = 0; k < 5; k++) {
        float w = 0.f;
        for (int c = 0; c < 64; c++) w += W_gat[k * 64 + c] * W_fc1[c * 128 + t];
        consts[144 + k * 128 + t] = w;
    }
}

// ---------------- sum(edge_attr) ----------------
__global__ void k_easum(const float* __restrict__ ea, float* __restrict__ consts, int n) {
    __shared__ float s[256];
    int i = blockIdx.x * blockDim.x + threadIdx.x;
    float v = (i < n) ? ea[i] : 0.f;
    s[threadIdx.x] = v;
    __syncthreads();
    for (int o = 128; o > 0; o >>= 1) {
        if (threadIdx.x < o) s[threadIdx.x] += s[threadIdx.x + o];
        __syncthreads();
    }
    if (threadIdx.x == 0) atomicAdd(&consts[0], s[0]);
}

// ---------------- per-node: a_s, a_d ----------------
__global__ void k_nodes(const float* __restrict__ x, const float* __restrict__ consts,
                        float* __restrict__ a_s, float* __restrict__ a_d, int n) {
    int i = blockIdx.x * blockDim.x + threadIdx.x;
    if (i >= n) return;
    const float* xi = x + (size_t)i * 5;
    float x0 = xi[0], x1 = xi[1], x2 = xi[2], x3 = xi[3], x4 = xi[4];
    a_s[i] = x0 * consts[2] + x1 * consts[3] + x2 * consts[4] + x3 * consts[5] + x4 * consts[6];
    a_d[i] = x0 * consts[7] + x1 * consts[8] + x2 * consts[9] + x3 * consts[10] + x4 * consts[11];
}

// ---------------- fused edge pass: ex = exp(lrelu(alpha)); scatter {ex*x, ex} ----------------
// rec layout: [8 copies][N][6]; copy = physical XCD id, so all atomics to a given
// line come from one XCD only -> workgroup-scope (L2-local) atomics are sufficient.
__global__ void k_edge(const int* __restrict__ src, const int* __restrict__ dst,
                       const float* __restrict__ ea, const float* __restrict__ a_s,
                       const float* __restrict__ a_d, const float* __restrict__ consts,
                       const float* __restrict__ x, float* __restrict__ rec, int E, int N) {
    int e = blockIdx.x * blockDim.x + threadIdx.x;
    if (e >= E) return;
    unsigned c = xcc_id();
    int s = src[e], d = dst[e];
    float al = lrelu(a_s[s] + a_d[d] + consts[1] * ea[e]);
    float ex = __expf(al);
    const float* xs = x + (size_t)s * 5;
    float* r = rec + ((size_t)c * N + (size_t)d) * 6;
    xcd_atomic_add(r + 0, ex * xs[0]);
    xcd_atomic_add(r + 1, ex * xs[1]);
    xcd_atomic_add(r + 2, ex * xs[2]);
    xcd_atomic_add(r + 3, ex * xs[3]);
    xcd_atomic_add(r + 4, ex * xs[4]);
    xcd_atomic_add(r + 5, ex);
}

// ---------------- per-node: reduce 8 copies, normalize, fc1+relu, pooled accumulate ----------------
// pool_batch is sorted -> register-accumulate per batch run, flush on change.
__global__ void k_pool(const float* __restrict__ x, const float* __restrict__ consts,
                       const float* __restrict__ a_s, const float* __restrict__ a_d,
                       const float* __restrict__ rec, const int* __restrict__ pool_batch,
                       float* __restrict__ g_sum, float* __restrict__ bcnt,
                       int N, float inv_E, int chunk) {
    int l = threadIdx.x;  // 128 threads = fc1 channels
    int start = blockIdx.x * chunk;
    if (start >= N) return;
    int end = start + chunk;
    if (end > N) end = N;
    float w0 = consts[144 + l], w1 = consts[272 + l], w2 = consts[400 + l],
          w3 = consts[528 + l], w4 = consts[656 + l];
    float bc = consts[16 + l];
    float cedge = consts[1];
    float mean_ea = consts[0] * inv_E;
    int cur_b = pool_batch[start];
    float accum = 0.f, cnt = 0.f;
    for (int i = start; i < end; ++i) {
        const float* r = rec + (size_t)i * 6;
        float y0 = 0, y1 = 0, y2 = 0, y3 = 0, y4 = 0, ssum = 0;
#pragma unroll
        for (int c = 0; c < 8; ++c) {
            const float* rc = r + (size_t)c * N * 6;
            y0 += rc[0]; y1 += rc[1]; y2 += rc[2]; y3 += rc[3]; y4 += rc[4]; ssum += rc[5];
        }
        float aself = lrelu(a_s[i] + a_d[i] + cedge * mean_ea);
        float exs = __expf(aself);
        const float* xi = x + (size_t)i * 5;
        float inv = 1.f / (ssum + exs + 1e-16f);
        y0 = (y0 + exs * xi[0]) * inv;
        y1 = (y1 + exs * xi[1]) * inv;
        y2 = (y2 + exs * xi[2]) * inv;
        y3 = (y3 + exs * xi[3]) * inv;
        y4 = (y4 + exs * xi[4]) * inv;
        float h = bc + y0 * w0 + y1 * w1 + y2 * w2 + y3 * w3 + y4 * w4;
        h = fmaxf(h, 0.f);
        int b = pool_batch[i];
        if (b != cur_b) {
            atomicAdd(&g_sum[cur_b * 128 + l], accum);
            if (l == 0) atomicAdd(&bcnt[cur_b], cnt);
            cur_b = b; accum = 0.f; cnt = 0.f;
        }
        accum += h;
        cnt += 1.f;
    }
    atomicAdd(&g_sum[cur_b * 128 + l], accum);
    if (l == 0) atomicAdd(&bcnt[cur_b], cnt);
}

// ---------------- head MLP: one block per batch row ----------------
__global__ void k_head(const float* __restrict__ g_sum, const float* __restrict__ bcnt,
                       const float* __restrict__ agent_state, const float* __restrict__ W_fc2,
                       const float* __restrict__ b_fc2, const float* __restrict__ W_v1,
                       const float* __restrict__ b_v1, const float* __restrict__ W_v2,
                       const float* __restrict__ b_v2, const float* __restrict__ W_a1,
                       const float* __restrict__ b_a1, const float* __restrict__ W_a2,
                       const float* __restrict__ b_a2, float* __restrict__ out, int A) {
    __shared__ float z[192];
    __shared__ float v1s[128], a1s[128], red[128];
    __shared__ float advs[8];
    int b = blockIdx.x, t = threadIdx.x;  // 128 threads
    float cnt = bcnt[b];
    cnt = cnt < 1.f ? 1.f : cnt;
    z[t] = g_sum[b * 128 + t] / cnt;
    if (t < 64) {
        float a = b_fc2[t];
        const float* as_ = agent_state + b * 34;
        for (int k = 0; k < 34; k++) a += as_[k] * W_fc2[k * 64 + t];
        z[128 + t] = fmaxf(a, 0.f);
    }
    __syncthreads();
    float v = b_v1[t], a = b_a1[t];
    for (int j = 0; j < 192; j++) {
        float zj = z[j];
        v += zj * W_v1[j * 128 + t];
        a += zj * W_a1[j * 128 + t];
    }
    v1s[t] = fmaxf(v, 0.f);
    a1s[t] = fmaxf(a, 0.f);
    __syncthreads();
    red[t] = v1s[t] * W_v2[t];
    __syncthreads();
    for (int o = 64; o > 0; o >>= 1) {
        if (t < o) red[t] += red[t + o];
        __syncthreads();
    }
    float value = red[0] + b_v2[0];
    if (t < A) {
        float ad = b_a2[t];
        for (int j = 0; j < 128; j++) ad += a1s[j] * W_a2[j * A + t];
        advs[t] = ad;
    }
    __syncthreads();
    if (t == 0) {
        float m = 0.f;
        for (int j = 0; j < A; j++) m += advs[j];
        m *= (1.f / (float)A);
        for (int j = 0; j < A; j++) out[b * A + j] = value + advs[j] - m;
    }
}

extern "C" void kernel_launch(void* const* d_in, const int* in_sizes, int n_in,
                              void* d_out, int out_size, void* d_ws, size_t ws_size,
                              hipStream_t stream) {
    const float* x        = (const float*)d_in[0];
    const int* edge_index = (const int*)d_in[1];
    const float* ea       = (const float*)d_in[2];
    const float* agent    = (const float*)d_in[3];
    const int* pool_batch = (const int*)d_in[4];
    const float* W_gat    = (const float*)d_in[5];
    const float* att_src  = (const float*)d_in[6];
    const float* att_dst  = (const float*)d_in[7];
    const float* W_edge   = (const float*)d_in[8];
    const float* att_edge = (const float*)d_in[9];
    const float* b_gat    = (const float*)d_in[10];
    const float* W_fc1    = (const float*)d_in[11];
    const float* b_fc1    = (const float*)d_in[12];
    const float* W_fc2    = (const float*)d_in[13];
    const float* b_fc2    = (const float*)d_in[14];
    const float* W_v1     = (const float*)d_in[15];
    const float* b_v1     = (const float*)d_in[16];
    const float* W_v2     = (const float*)d_in[17];
    const float* b_v2     = (const float*)d_in[18];
    const float* W_a1     = (const float*)d_in[19];
    const float* b_a1     = (const float*)d_in[20];
    const float* W_a2     = (const float*)d_in[21];
    const float* b_a2     = (const float*)d_in[22];

    const int N = in_sizes[0] / 5;
    const int E = in_sizes[2];
    const int B = in_sizes[3] / 34;
    const int A = out_size / B;
    const float inv_E = 1.0f / (float)E;

    const int* src = edge_index;
    const int* dst = edge_index + E;

    // ---- ws layout (bytes), zero-region first ----
    char* ws = (char*)d_ws;
    size_t off = 0;
    auto take = [&](size_t bytes) {
        size_t o = off;
        off = (off + bytes + 255) & ~(size_t)255;
        return o;
    };
    size_t o_consts = take(4096);                         // zeroed
    size_t o_rec    = take((size_t)8 * N * 6 * 4);        // zeroed (8 XCD copies)
    size_t o_gsum   = take((size_t)B * 128 * 4);          // zeroed
    size_t o_bcnt   = take((size_t)B * 4);                // zeroed
    size_t zero_bytes = off;
    size_t o_as   = take((size_t)N * 4);
    size_t o_ad   = take((size_t)N * 4);
    (void)ws_size;

    float* consts = (float*)(ws + o_consts);
    float* rec    = (float*)(ws + o_rec);
    float* g_sum  = (float*)(ws + o_gsum);
    float* bcnt   = (float*)(ws + o_bcnt);
    float* a_s    = (float*)(ws + o_as);
    float* a_d    = (float*)(ws + o_ad);

    hipMemsetAsync(d_ws, 0, zero_bytes, stream);

    k_setup<<<1, 128, 0, stream>>>(W_gat, att_src, att_dst, W_edge, att_edge, b_gat, W_fc1, b_fc1, consts);

    int ebl = (E + 255) / 256;
    int nbl = (N + 255) / 256;
    k_easum<<<ebl, 256, 0, stream>>>(ea, consts, E);
    k_nodes<<<nbl, 256, 0, stream>>>(x, consts, a_s, a_d, N);
    k_edge<<<ebl, 256, 0, stream>>>(src, dst, ea, a_s, a_d, consts, x, rec, E, N);
    const int chunk = 256;
    int pbl = (N + chunk - 1) / chunk;
    k_pool<<<pbl, 128, 0, stream>>>(x, consts, a_s, a_d, rec, pool_batch, g_sum, bcnt, N, inv_E, chunk);
    k_head<<<B, 128, 0, stream>>>(g_sum, bcnt, agent, W_fc2, b_fc2, W_v1, b_v1, W_v2, b_v2,
                                  W_a1, b_a1, W_a2, b_a2, (float*)d_out, A);
}

// Round 3
// 285.584 us; speedup vs baseline: 3.7978x; 2.6451x over previous
//
#include <hip/hip_runtime.h>
#include <math.h>

#define NPB 2730   // nodes per bucket: 2730*6*4 = 65520 B LDS accumulator
#define MAXR 64    // max buckets supported

static __device__ __forceinline__ float lrelu(float x) { return x > 0.0f ? x : 0.2f * x; }

// consts layout (floats):
// [0] sum_ea (atomic), [1] c_edge, [2..6] va, [7..11] vd, [16..143] bc, [144..783] Wc[5][128]

__global__ void k_setup(const float* __restrict__ W_gat, const float* __restrict__ att_src,
                        const float* __restrict__ att_dst, const float* __restrict__ W_edge,
                        const float* __restrict__ att_edge, const float* __restrict__ b_gat,
                        const float* __restrict__ W_fc1, const float* __restrict__ b_fc1,
                        float* __restrict__ consts) {
    int t = threadIdx.x;  // 128 threads
    if (t == 0) {
        float c = 0.f;
        for (int k = 0; k < 64; k++) c += W_edge[k] * att_edge[k];
        consts[1] = c;
    }
    if (t < 5) {
        float a = 0.f, b = 0.f;
        for (int c = 0; c < 64; c++) {
            float w = W_gat[t * 64 + c];
            a += w * att_src[c];
            b += w * att_dst[c];
        }
        consts[2 + t] = a;
        consts[7 + t] = b;
    }
    float bcv = b_fc1[t];
    for (int c = 0; c < 64; c++) bcv += b_gat[c] * W_fc1[c * 128 + t];
    consts[16 + t] = bcv;
    for (int k = 0; k < 5; k++) {
        float w = 0.f;
        for (int c = 0; c < 64; c++) w += W_gat[k * 64 + c] * W_fc1[c * 128 + t];
        consts[144 + k * 128 + t] = w;
    }
}

__global__ void k_easum(const float* __restrict__ ea, float* __restrict__ consts, int n) {
    __shared__ float s[256];
    int i = blockIdx.x * blockDim.x + threadIdx.x;
    s[threadIdx.x] = (i < n) ? ea[i] : 0.f;
    __syncthreads();
    for (int o = 128; o > 0; o >>= 1) {
        if (threadIdx.x < o) s[threadIdx.x] += s[threadIdx.x + o];
        __syncthreads();
    }
    if (threadIdx.x == 0) atomicAdd(&consts[0], s[0]);
}

__global__ void k_nodes(const float* __restrict__ x, const float* __restrict__ consts,
                        float* __restrict__ a_s, float* __restrict__ a_d, int n) {
    int i = blockIdx.x * blockDim.x + threadIdx.x;
    if (i >= n) return;
    const float* xi = x + (size_t)i * 5;
    float x0 = xi[0], x1 = xi[1], x2 = xi[2], x3 = xi[3], x4 = xi[4];
    a_s[i] = x0 * consts[2] + x1 * consts[3] + x2 * consts[4] + x3 * consts[5] + x4 * consts[6];
    a_d[i] = x0 * consts[7] + x1 * consts[8] + x2 * consts[9] + x3 * consts[10] + x4 * consts[11];
}

// batch_start[b] for b in [0,B]; pool_batch sorted ascending
__global__ void k_bstart(const int* __restrict__ pb, int* __restrict__ bstart, int N, int B) {
    int i = blockIdx.x * blockDim.x + threadIdx.x;
    if (i >= N) return;
    int cur = pb[i];
    int prev = (i == 0) ? -1 : pb[i - 1];
    for (int b = prev + 1; b <= cur; b++) bstart[b] = i;
    if (i == N - 1)
        for (int b = cur + 1; b <= B; b++) bstart[b] = N;
}

// ---- phase 1: per-edge ex, bin records into per-bucket slabs ----
// record: {u32 (src<<12)|dstLocal, f32 ex}
__global__ void k_p1(const int* __restrict__ src, const int* __restrict__ dst,
                     const float* __restrict__ ea, const float* __restrict__ a_s,
                     const float* __restrict__ a_d, const float* __restrict__ consts,
                     uint2* __restrict__ slab, unsigned* __restrict__ gcur,
                     int E, int R, int CAP) {
    __shared__ unsigned hist[MAXR], base[MAXR];
    int t = threadIdx.x;  // 256
    if (t < R) hist[t] = 0;
    __syncthreads();
    int e0 = blockIdx.x * 4096;
    int e1 = e0 + 4096; if (e1 > E) e1 = E;
    for (int e = e0 + t; e < e1; e += 256) {
        unsigned b = (unsigned)dst[e] / NPB;
        atomicAdd(&hist[b], 1u);
    }
    __syncthreads();
    if (t < R) { base[t] = atomicAdd(&gcur[t], hist[t]); hist[t] = 0; }
    __syncthreads();
    float ce = consts[1];
    for (int e = e0 + t; e < e1; e += 256) {
        int d = dst[e], s = src[e];
        unsigned b = (unsigned)d / NPB;
        unsigned dl = (unsigned)d - b * NPB;
        float al = lrelu(a_s[s] + a_d[d] + ce * ea[e]);
        float ex = __expf(al);
        unsigned slot = base[b] + atomicAdd(&hist[b], 1u);
        if (slot < (unsigned)CAP)
            slab[(size_t)b * CAP + slot] = make_uint2(((unsigned)s << 12) | dl, __float_as_uint(ex));
    }
}

// ---- phase 2: per (bucket r, slice s) LDS aggregation -> partial copy ----
__global__ void __launch_bounds__(256, 1) k_p2(const uint2* __restrict__ slab,
                     const unsigned* __restrict__ gcur, const float* __restrict__ x,
                     float* __restrict__ partials, int S, int CAP) {
    __shared__ float acc[NPB * 6];
    int t = threadIdx.x;  // 256
    int s = blockIdx.x, r = blockIdx.y;
    for (int i = t; i < NPB * 6; i += 256) acc[i] = 0.f;
    __syncthreads();
    unsigned cnt = gcur[r]; if (cnt > (unsigned)CAP) cnt = CAP;
    unsigned L = (cnt + S - 1) / S;
    unsigned i0 = (unsigned)s * L;
    unsigned i1 = i0 + L; if (i1 > cnt) i1 = cnt;
    const uint2* sl = slab + (size_t)r * CAP;
    for (unsigned i = i0 + t; i < i1; i += 256) {
        uint2 rec = sl[i];
        unsigned dl = rec.x & 4095u;
        unsigned sr = rec.x >> 12;
        float ex = __uint_as_float(rec.y);
        const float* xs = x + (size_t)sr * 5;
        float* a = acc + dl * 6;
        atomicAdd(a + 0, ex * xs[0]);
        atomicAdd(a + 1, ex * xs[1]);
        atomicAdd(a + 2, ex * xs[2]);
        atomicAdd(a + 3, ex * xs[3]);
        atomicAdd(a + 4, ex * xs[4]);
        atomicAdd(a + 5, ex);
    }
    __syncthreads();
    float* out = partials + ((size_t)r * S + s) * (NPB * 6);
    for (int i = t; i < NPB * 6; i += 256) out[i] = acc[i];
}

// ---- phase 3: merge partials + self-loop, normalize -> y[N][5] ----
__global__ void k_p3(const float* __restrict__ partials, const float* __restrict__ x,
                     const float* __restrict__ a_s, const float* __restrict__ a_d,
                     const float* __restrict__ consts, float* __restrict__ y,
                     int N, int S, float inv_E) {
    int i = blockIdx.x * blockDim.x + threadIdx.x;
    if (i >= N) return;
    unsigned r = (unsigned)i / NPB;
    unsigned dl = (unsigned)i - r * NPB;
    float y0 = 0, y1 = 0, y2 = 0, y3 = 0, y4 = 0, ss = 0;
    const float* p = partials + (size_t)r * S * (NPB * 6) + (size_t)dl * 6;
    for (int s = 0; s < S; s++) {
        const float* q = p + (size_t)s * (NPB * 6);
        y0 += q[0]; y1 += q[1]; y2 += q[2]; y3 += q[3]; y4 += q[4]; ss += q[5];
    }
    float mean_ea = consts[0] * inv_E;
    float aself = lrelu(a_s[i] + a_d[i] + consts[1] * mean_ea);
    float exs = __expf(aself);
    const float* xi = x + (size_t)i * 5;
    float inv = 1.f / (ss + exs + 1e-16f);
    y[(size_t)i * 5 + 0] = (y0 + exs * xi[0]) * inv;
    y[(size_t)i * 5 + 1] = (y1 + exs * xi[1]) * inv;
    y[(size_t)i * 5 + 2] = (y2 + exs * xi[2]) * inv;
    y[(size_t)i * 5 + 3] = (y3 + exs * xi[3]) * inv;
    y[(size_t)i * 5 + 4] = (y4 + exs * xi[4]) * inv;
}

// ---- pool: 2 blocks per batch, register accumulate, direct store (no atomics) ----
__global__ void k_pool(const float* __restrict__ y, const float* __restrict__ consts,
                       const int* __restrict__ bstart, float* __restrict__ g2, int B) {
    int l = threadIdx.x;  // 128 threads
    int b = blockIdx.x >> 1, half = blockIdx.x & 1;
    int st = bstart[b], en = bstart[b + 1];
    int len = en - st;
    int h0 = (len + 1) >> 1;
    int i0 = half ? st + h0 : st;
    int i1 = half ? en : st + h0;
    float w0 = consts[144 + l], w1 = consts[272 + l], w2 = consts[400 + l],
          w3 = consts[528 + l], w4 = consts[656 + l];
    float bc = consts[16 + l];
    float accum = 0.f;
    for (int i = i0; i < i1; ++i) {
        const float* yi = y + (size_t)i * 5;
        float h = bc + yi[0] * w0 + yi[1] * w1 + yi[2] * w2 + yi[3] * w3 + yi[4] * w4;
        accum += fmaxf(h, 0.f);
    }
    g2[((size_t)half * B + b) * 128 + l] = accum;
}

// ---- head MLP: one block per batch row ----
__global__ void k_head(const float* __restrict__ g2, const int* __restrict__ bstart,
                       const float* __restrict__ agent_state, const float* __restrict__ W_fc2,
                       const float* __restrict__ b_fc2, const float* __restrict__ W_v1,
                       const float* __restrict__ b_v1, const float* __restrict__ W_v2,
                       const float* __restrict__ b_v2, const float* __restrict__ W_a1,
                       const float* __restrict__ b_a1, const float* __restrict__ W_a2,
                       const float* __restrict__ b_a2, float* __restrict__ out, int A, int B) {
    __shared__ float z[192];
    __shared__ float v1s[128], a1s[128], red[128];
    __shared__ float advs[8];
    int b = blockIdx.x, t = threadIdx.x;  // 128 threads
    float cnt = (float)(bstart[b + 1] - bstart[b]);
    cnt = cnt < 1.f ? 1.f : cnt;
    z[t] = (g2[(size_t)b * 128 + t] + g2[((size_t)B + b) * 128 + t]) / cnt;
    if (t < 64) {
        float a = b_fc2[t];
        const float* as_ = agent_state + b * 34;
        for (int k = 0; k < 34; k++) a += as_[k] * W_fc2[k * 64 + t];
        z[128 + t] = fmaxf(a, 0.f);
    }
    __syncthreads();
    float v = b_v1[t], a = b_a1[t];
    for (int j = 0; j < 192; j++) {
        float zj = z[j];
        v += zj * W_v1[j * 128 + t];
        a += zj * W_a1[j * 128 + t];
    }
    v1s[t] = fmaxf(v, 0.f);
    a1s[t] = fmaxf(a, 0.f);
    __syncthreads();
    red[t] = v1s[t] * W_v2[t];
    __syncthreads();
    for (int o = 64; o > 0; o >>= 1) {
        if (t < o) red[t] += red[t + o];
        __syncthreads();
    }
    float value = red[0] + b_v2[0];
    if (t < A) {
        float ad = b_a2[t];
        for (int j = 0; j < 128; j++) ad += a1s[j] * W_a2[j * A + t];
        advs[t] = ad;
    }
    __syncthreads();
    if (t == 0) {
        float m = 0.f;
        for (int j = 0; j < A; j++) m += advs[j];
        m *= (1.f / (float)A);
        for (int j = 0; j < A; j++) out[b * A + j] = value + advs[j] - m;
    }
}

extern "C" void kernel_launch(void* const* d_in, const int* in_sizes, int n_in,
                              void* d_out, int out_size, void* d_ws, size_t ws_size,
                              hipStream_t stream) {
    const float* x        = (const float*)d_in[0];
    const int* edge_index = (const int*)d_in[1];
    const float* ea       = (const float*)d_in[2];
    const float* agent    = (const float*)d_in[3];
    const int* pool_batch = (const int*)d_in[4];
    const float* W_gat    = (const float*)d_in[5];
    const float* att_src  = (const float*)d_in[6];
    const float* att_dst  = (const float*)d_in[7];
    const float* W_edge   = (const float*)d_in[8];
    const float* att_edge = (const float*)d_in[9];
    const float* b_gat    = (const float*)d_in[10];
    const float* W_fc1    = (const float*)d_in[11];
    const float* b_fc1    = (const float*)d_in[12];
    const float* W_fc2    = (const float*)d_in[13];
    const float* b_fc2    = (const float*)d_in[14];
    const float* W_v1     = (const float*)d_in[15];
    const float* b_v1     = (const float*)d_in[16];
    const float* W_v2     = (const float*)d_in[17];
    const float* b_v2     = (const float*)d_in[18];
    const float* W_a1     = (const float*)d_in[19];
    const float* b_a1     = (const float*)d_in[20];
    const float* W_a2     = (const float*)d_in[21];
    const float* b_a2     = (const float*)d_in[22];

    const int N = in_sizes[0] / 5;
    const int E = in_sizes[2];
    const int B = in_sizes[3] / 34;
    const int A = out_size / B;
    const float inv_E = 1.0f / (float)E;

    const int* src = edge_index;
    const int* dst = edge_index + E;

    const int R = (N + NPB - 1) / NPB;                 // buckets (38)
    int capBase = (int)(((long long)E * NPB) / N);     // expected records/bucket
    const int CAP = capBase + capBase / 16 + 256;      // ~13 sigma margin

    // ---- ws layout ----
    char* ws = (char*)d_ws;
    size_t off = 0;
    auto take = [&](size_t bytes) {
        size_t o = off;
        off = (off + bytes + 255) & ~(size_t)255;
        return o;
    };
    size_t o_consts = take(4096);                      // zeroed
    size_t o_gcur   = take((size_t)MAXR * 4);          // zeroed
    size_t zero_bytes = off;
    size_t o_as     = take((size_t)N * 4);
    size_t o_ad     = take((size_t)N * 4);
    size_t o_y      = take((size_t)N * 5 * 4);
    size_t o_bstart = take((size_t)(B + 1) * 4);
    size_t o_g2     = take((size_t)2 * B * 128 * 4);
    size_t o_slab   = take((size_t)R * CAP * 8);
    size_t o_part   = off;  // rest: partials, S copies of R*NPB*6 floats
    size_t perS = (size_t)R * NPB * 6 * 4;
    int S = 8;
    while (S > 1 && o_part + (size_t)S * perS > ws_size) S--;

    float* consts   = (float*)(ws + o_consts);
    unsigned* gcur  = (unsigned*)(ws + o_gcur);
    float* a_s      = (float*)(ws + o_as);
    float* a_d      = (float*)(ws + o_ad);
    float* y        = (float*)(ws + o_y);
    int* bstart     = (int*)(ws + o_bstart);
    float* g2       = (float*)(ws + o_g2);
    uint2* slab     = (uint2*)(ws + o_slab);
    float* partials = (float*)(ws + o_part);

    hipMemsetAsync(d_ws, 0, zero_bytes, stream);

    k_setup<<<1, 128, 0, stream>>>(W_gat, att_src, att_dst, W_edge, att_edge, b_gat, W_fc1, b_fc1, consts);

    int nbl = (N + 255) / 256;
    k_easum<<<(E + 255) / 256, 256, 0, stream>>>(ea, consts, E);
    k_nodes<<<nbl, 256, 0, stream>>>(x, consts, a_s, a_d, N);
    k_bstart<<<nbl, 256, 0, stream>>>(pool_batch, bstart, N, B);
    k_p1<<<(E + 4095) / 4096, 256, 0, stream>>>(src, dst, ea, a_s, a_d, consts, slab, gcur, E, R, CAP);
    dim3 g2grid(S, R);
    k_p2<<<g2grid, 256, 0, stream>>>(slab, gcur, x, partials, S, CAP);
    k_p3<<<nbl, 256, 0, stream>>>(partials, x, a_s, a_d, consts, y, N, S, inv_E);
    k_pool<<<2 * B, 128, 0, stream>>>(y, consts, bstart, g2, B);
    k_head<<<B, 128, 0, stream>>>(g2, bstart, agent, W_fc2, b_fc2, W_v1, b_v1, W_v2, b_v2,
                                  W_a1, b_a1, W_a2, b_a2, (float*)d_out, A, B);
}

// Round 4
// 250.039 us; speedup vs baseline: 4.3377x; 1.1422x over previous
//
#include <hip/hip_runtime.h>
#include <math.h>

#define NPB   512      // nodes per bucket (N=102400 = 200*512 exactly)
#define NPBL  9
#define MAXR  256      // max buckets
#define TILE  2048     // edges per k_p1 block
#define RPT   8        // records per thread in k_p1
#define GCS   16       // gcur stride in u32 (64B line padding)

static __device__ __forceinline__ float lrelu(float x) { return x > 0.0f ? x : 0.2f * x; }

// consts layout (floats):
// [0] sum_ea (atomic), [1] c_edge, [2..6] va, [7..11] vd, [16..143] bc, [144..783] Wc[5][128]

__global__ void k_setup(const float* __restrict__ W_gat, const float* __restrict__ att_src,
                        const float* __restrict__ att_dst, const float* __restrict__ W_edge,
                        const float* __restrict__ att_edge, const float* __restrict__ b_gat,
                        const float* __restrict__ W_fc1, const float* __restrict__ b_fc1,
                        float* __restrict__ consts) {
    int t = threadIdx.x;  // 128 threads
    if (t == 0) {
        float c = 0.f;
        for (int k = 0; k < 64; k++) c += W_edge[k] * att_edge[k];
        consts[1] = c;
    }
    if (t < 5) {
        float a = 0.f, b = 0.f;
        for (int c = 0; c < 64; c++) {
            float w = W_gat[t * 64 + c];
            a += w * att_src[c];
            b += w * att_dst[c];
        }
        consts[2 + t] = a;
        consts[7 + t] = b;
    }
    float bcv = b_fc1[t];
    for (int c = 0; c < 64; c++) bcv += b_gat[c] * W_fc1[c * 128 + t];
    consts[16 + t] = bcv;
    for (int k = 0; k < 5; k++) {
        float w = 0.f;
        for (int c = 0; c < 64; c++) w += W_gat[k * 64 + c] * W_fc1[c * 128 + t];
        consts[144 + k * 128 + t] = w;
    }
}

__global__ void k_easum(const float* __restrict__ ea, float* __restrict__ consts, int n) {
    __shared__ float s[256];
    int i = blockIdx.x * blockDim.x + threadIdx.x;
    s[threadIdx.x] = (i < n) ? ea[i] : 0.f;
    __syncthreads();
    for (int o = 128; o > 0; o >>= 1) {
        if (threadIdx.x < o) s[threadIdx.x] += s[threadIdx.x + o];
        __syncthreads();
    }
    if (threadIdx.x == 0) atomicAdd(&consts[0], s[0]);
}

// per-node: xs8 = {x0..x4, a_s, 0, 0} (32B struct, line-aligned), a_d separate
__global__ void k_nodes(const float* __restrict__ x, const float* __restrict__ consts,
                        float* __restrict__ xs8, float* __restrict__ a_d, int n) {
    int i = blockIdx.x * blockDim.x + threadIdx.x;
    if (i >= n) return;
    const float* xi = x + (size_t)i * 5;
    float x0 = xi[0], x1 = xi[1], x2 = xi[2], x3 = xi[3], x4 = xi[4];
    float as = x0 * consts[2] + x1 * consts[3] + x2 * consts[4] + x3 * consts[5] + x4 * consts[6];
    float ad = x0 * consts[7] + x1 * consts[8] + x2 * consts[9] + x3 * consts[10] + x4 * consts[11];
    float* o = xs8 + (size_t)i * 8;
    o[0] = x0; o[1] = x1; o[2] = x2; o[3] = x3; o[4] = x4;
    o[5] = as; o[6] = 0.f; o[7] = 0.f;
    a_d[i] = ad;
}

__global__ void k_bstart(const int* __restrict__ pb, int* __restrict__ bstart, int N, int B) {
    int i = blockIdx.x * blockDim.x + threadIdx.x;
    if (i >= N) return;
    int cur = pb[i];
    int prev = (i == 0) ? -1 : pb[i - 1];
    for (int b = prev + 1; b <= cur; b++) bstart[b] = i;
    if (i == N - 1)
        for (int b = cur + 1; b <= B; b++) bstart[b] = N;
}

// ---- phase 1: bin edges by dst bucket; LDS counting sort -> coalesced slab flush ----
// record: {u32 (src<<9)|dstLocal, f32 c_edge*ea[e]}  (no gathers in this kernel)
__global__ void k_p1(const int* __restrict__ src, const int* __restrict__ dst,
                     const float* __restrict__ ea, const float* __restrict__ consts,
                     uint2* __restrict__ slab, unsigned* __restrict__ gcur,
                     int E, int R, int CAP) {
    __shared__ unsigned hist[MAXR], lbase[MAXR], gbase[MAXR], scan[256];
    __shared__ uint2 staged[TILE];
    __shared__ unsigned char bof[TILE];
    int t = threadIdx.x;  // 256
    int e0 = blockIdx.x * TILE;
    int n = E - e0; if (n > TILE) n = TILE;
    for (int i = t; i < MAXR; i += 256) hist[i] = 0;
    __syncthreads();
    unsigned key[RPT]; float val[RPT]; unsigned brk[RPT];
    float ce = consts[1];
#pragma unroll
    for (int k = 0; k < RPT; k++) {
        int idx = t + k * 256;
        brk[k] = 0xFFFFFFFFu;
        if (idx < n) {
            int e = e0 + idx;
            int d = dst[e];
            unsigned b = (unsigned)d >> NPBL;
            key[k] = ((unsigned)src[e] << NPBL) | ((unsigned)d & (NPB - 1));
            val[k] = ce * ea[e];
            unsigned r = atomicAdd(&hist[b], 1u);
            brk[k] = (b << 12) | r;   // b<=255 (8b), rank<2048 (12b)
        }
    }
    __syncthreads();
    unsigned v = (t < R) ? hist[t] : 0;
    if (t < R) gbase[t] = atomicAdd(&gcur[t * GCS], v);
    scan[t] = v;
    __syncthreads();
    for (int off = 1; off < 256; off <<= 1) {
        unsigned add = (t >= off) ? scan[t - off] : 0;
        __syncthreads();
        scan[t] += add;
        __syncthreads();
    }
    if (t < R) lbase[t] = scan[t] - v;
    __syncthreads();
#pragma unroll
    for (int k = 0; k < RPT; k++) {
        if (brk[k] != 0xFFFFFFFFu) {
            unsigned b = brk[k] >> 12, r = brk[k] & 4095u;
            unsigned pos = lbase[b] + r;
            staged[pos] = make_uint2(key[k], __float_as_uint(val[k]));
            bof[pos] = (unsigned char)b;
        }
    }
    __syncthreads();
    for (int i = t; i < n; i += 256) {
        unsigned b = bof[i];
        unsigned slot = gbase[b] + (unsigned)i - lbase[b];
        if (slot < (unsigned)CAP) slab[(size_t)b * CAP + slot] = staged[i];
    }
}

// ---- phase 2: per (slice s, bucket r): small-LDS aggregation, high occupancy ----
__global__ void k_p2(const uint2* __restrict__ slab, const unsigned* __restrict__ gcur,
                     const float* __restrict__ xs8, const float* __restrict__ a_d,
                     float* __restrict__ partials, int S, int CAP, int N) {
    __shared__ float acc[NPB * 6];   // 12.3 KB
    __shared__ float adl[NPB];       // 2 KB
    int t = threadIdx.x;  // 256
    int s = blockIdx.x, r = blockIdx.y;
    for (int i = t; i < NPB * 6; i += 256) acc[i] = 0.f;
    for (int i = t; i < NPB; i += 256) {
        int node = r * NPB + i;
        adl[i] = (node < N) ? a_d[node] : 0.f;
    }
    __syncthreads();
    unsigned cnt = gcur[r * GCS]; if (cnt > (unsigned)CAP) cnt = CAP;
    unsigned L = (cnt + (unsigned)S - 1) / (unsigned)S;
    unsigned i0 = (unsigned)s * L, i1 = i0 + L; if (i1 > cnt) i1 = cnt;
    const uint2* sl = slab + (size_t)r * CAP;
    for (unsigned i = i0 + t; i < i1; i += 256) {
        uint2 rec = sl[i];
        unsigned dl = rec.x & (NPB - 1);
        unsigned sr = rec.x >> NPBL;
        const float* xp = xs8 + (size_t)sr * 8;   // one 64B-line gather
        float al = lrelu(xp[5] + adl[dl] + __uint_as_float(rec.y));
        float ex = __expf(al);
        float* a = acc + dl * 6;
        atomicAdd(a + 0, ex * xp[0]);
        atomicAdd(a + 1, ex * xp[1]);
        atomicAdd(a + 2, ex * xp[2]);
        atomicAdd(a + 3, ex * xp[3]);
        atomicAdd(a + 4, ex * xp[4]);
        atomicAdd(a + 5, ex);
    }
    __syncthreads();
    float* out = partials + (size_t)(r * S + s) * (NPB * 6);
    for (int i = t; i < NPB * 6; i += 256) out[i] = acc[i];
}

// ---- phase 3: merge S partials + self-loop, normalize -> y[N][5] ----
__global__ void k_p3(const float* __restrict__ partials, const float* __restrict__ xs8,
                     const float* __restrict__ a_d, const float* __restrict__ consts,
                     float* __restrict__ y, int N, int S, float inv_E) {
    int i = blockIdx.x * blockDim.x + threadIdx.x;
    if (i >= N) return;
    int r = i >> NPBL, dl = i & (NPB - 1);
    float y0 = 0, y1 = 0, y2 = 0, y3 = 0, y4 = 0, ss = 0;
    const float* p = partials + (size_t)r * S * (NPB * 6) + (size_t)dl * 6;
    for (int s = 0; s < S; s++) {
        const float* q = p + (size_t)s * (NPB * 6);
        y0 += q[0]; y1 += q[1]; y2 += q[2]; y3 += q[3]; y4 += q[4]; ss += q[5];
    }
    const float* xp = xs8 + (size_t)i * 8;
    float mean_ea = consts[0] * inv_E;
    float aself = lrelu(xp[5] + a_d[i] + consts[1] * mean_ea);
    float exs = __expf(aself);
    float inv = 1.f / (ss + exs + 1e-16f);
    y[(size_t)i * 5 + 0] = (y0 + exs * xp[0]) * inv;
    y[(size_t)i * 5 + 1] = (y1 + exs * xp[1]) * inv;
    y[(size_t)i * 5 + 2] = (y2 + exs * xp[2]) * inv;
    y[(size_t)i * 5 + 3] = (y3 + exs * xp[3]) * inv;
    y[(size_t)i * 5 + 4] = (y4 + exs * xp[4]) * inv;
}

// ---- pool: 2 blocks per batch, register accumulate, direct store (no atomics) ----
__global__ void k_pool(const float* __restrict__ y, const float* __restrict__ consts,
                       const int* __restrict__ bstart, float* __restrict__ g2, int B) {
    int l = threadIdx.x;  // 128 threads
    int b = blockIdx.x >> 1, half = blockIdx.x & 1;
    int st = bstart[b], en = bstart[b + 1];
    int len = en - st;
    int h0 = (len + 1) >> 1;
    int i0 = half ? st + h0 : st;
    int i1 = half ? en : st + h0;
    float w0 = consts[144 + l], w1 = consts[272 + l], w2 = consts[400 + l],
          w3 = consts[528 + l], w4 = consts[656 + l];
    float bc = consts[16 + l];
    float accum = 0.f;
    for (int i = i0; i < i1; ++i) {
        const float* yi = y + (size_t)i * 5;
        float h = bc + yi[0] * w0 + yi[1] * w1 + yi[2] * w2 + yi[3] * w3 + yi[4] * w4;
        accum += fmaxf(h, 0.f);
    }
    g2[((size_t)half * B + b) * 128 + l] = accum;
}

// ---- head MLP: one block per batch row ----
__global__ void k_head(const float* __restrict__ g2, const int* __restrict__ bstart,
                       const float* __restrict__ agent_state, const float* __restrict__ W_fc2,
                       const float* __restrict__ b_fc2, const float* __restrict__ W_v1,
                       const float* __restrict__ b_v1, const float* __restrict__ W_v2,
                       const float* __restrict__ b_v2, const float* __restrict__ W_a1,
                       const float* __restrict__ b_a1, const float* __restrict__ W_a2,
                       const float* __restrict__ b_a2, float* __restrict__ out, int A, int B) {
    __shared__ float z[192];
    __shared__ float v1s[128], a1s[128], red[128];
    __shared__ float advs[8];
    int b = blockIdx.x, t = threadIdx.x;  // 128 threads
    float cnt = (float)(bstart[b + 1] - bstart[b]);
    cnt = cnt < 1.f ? 1.f : cnt;
    z[t] = (g2[(size_t)b * 128 + t] + g2[((size_t)B + b) * 128 + t]) / cnt;
    if (t < 64) {
        float a = b_fc2[t];
        const float* as_ = agent_state + b * 34;
        for (int k = 0; k < 34; k++) a += as_[k] * W_fc2[k * 64 + t];
        z[128 + t] = fmaxf(a, 0.f);
    }
    __syncthreads();
    float v = b_v1[t], a = b_a1[t];
    for (int j = 0; j < 192; j++) {
        float zj = z[j];
        v += zj * W_v1[j * 128 + t];
        a += zj * W_a1[j * 128 + t];
    }
    v1s[t] = fmaxf(v, 0.f);
    a1s[t] = fmaxf(a, 0.f);
    __syncthreads();
    red[t] = v1s[t] * W_v2[t];
    __syncthreads();
    for (int o = 64; o > 0; o >>= 1) {
        if (t < o) red[t] += red[t + o];
        __syncthreads();
    }
    float value = red[0] + b_v2[0];
    if (t < A) {
        float ad = b_a2[t];
        for (int j = 0; j < 128; j++) ad += a1s[j] * W_a2[j * A + t];
        advs[t] = ad;
    }
    __syncthreads();
    if (t == 0) {
        float m = 0.f;
        for (int j = 0; j < A; j++) m += advs[j];
        m *= (1.f / (float)A);
        for (int j = 0; j < A; j++) out[b * A + j] = value + advs[j] - m;
    }
}

extern "C" void kernel_launch(void* const* d_in, const int* in_sizes, int n_in,
                              void* d_out, int out_size, void* d_ws, size_t ws_size,
                              hipStream_t stream) {
    const float* x        = (const float*)d_in[0];
    const int* edge_index = (const int*)d_in[1];
    const float* ea       = (const float*)d_in[2];
    const float* agent    = (const float*)d_in[3];
    const int* pool_batch = (const int*)d_in[4];
    const float* W_gat    = (const float*)d_in[5];
    const float* att_src  = (const float*)d_in[6];
    const float* att_dst  = (const float*)d_in[7];
    const float* W_edge   = (const float*)d_in[8];
    const float* att_edge = (const float*)d_in[9];
    const float* b_gat    = (const float*)d_in[10];
    const float* W_fc1    = (const float*)d_in[11];
    const float* b_fc1    = (const float*)d_in[12];
    const float* W_fc2    = (const float*)d_in[13];
    const float* b_fc2    = (const float*)d_in[14];
    const float* W_v1     = (const float*)d_in[15];
    const float* b_v1     = (const float*)d_in[16];
    const float* W_v2     = (const float*)d_in[17];
    const float* b_v2     = (const float*)d_in[18];
    const float* W_a1     = (const float*)d_in[19];
    const float* b_a1     = (const float*)d_in[20];
    const float* W_a2     = (const float*)d_in[21];
    const float* b_a2     = (const float*)d_in[22];

    const int N = in_sizes[0] / 5;
    const int E = in_sizes[2];
    const int B = in_sizes[3] / 34;
    const int A = out_size / B;
    const float inv_E = 1.0f / (float)E;

    const int* src = edge_index;
    const int* dst = edge_index + E;

    const int R = (N + NPB - 1) / NPB;            // 200 buckets
    int capBase = (E + R - 1) / R;                // ~8192
    const int CAP = capBase + capBase / 16 + 256; // ~8.5 sigma margin

    // ---- ws layout ----
    char* ws = (char*)d_ws;
    size_t off = 0;
    auto take = [&](size_t bytes) {
        size_t o = off;
        off = (off + bytes + 255) & ~(size_t)255;
        return o;
    };
    size_t o_consts = take(4096);                       // zeroed
    size_t o_gcur   = take((size_t)MAXR * GCS * 4);     // zeroed (64B-padded counters)
    size_t zero_bytes = off;
    size_t o_xs8    = take((size_t)N * 8 * 4);
    size_t o_ad     = take((size_t)N * 4);
    size_t o_y      = take((size_t)N * 5 * 4);
    size_t o_bstart = take((size_t)(B + 1) * 4);
    size_t o_g2     = take((size_t)2 * B * 128 * 4);
    size_t o_slab   = take((size_t)R * CAP * 8);
    size_t o_part   = off;
    size_t perS = (size_t)R * NPB * 6 * 4;
    int S = 8;
    while (S > 1 && o_part + (size_t)S * perS > ws_size) S--;

    float* consts   = (float*)(ws + o_consts);
    unsigned* gcur  = (unsigned*)(ws + o_gcur);
    float* xs8      = (float*)(ws + o_xs8);
    float* a_d      = (float*)(ws + o_ad);
    float* y        = (float*)(ws + o_y);
    int* bstart     = (int*)(ws + o_bstart);
    float* g2       = (float*)(ws + o_g2);
    uint2* slab     = (uint2*)(ws + o_slab);
    float* partials = (float*)(ws + o_part);

    hipMemsetAsync(d_ws, 0, zero_bytes, stream);

    k_setup<<<1, 128, 0, stream>>>(W_gat, att_src, att_dst, W_edge, att_edge, b_gat, W_fc1, b_fc1, consts);

    int nbl = (N + 255) / 256;
    k_easum<<<(E + 255) / 256, 256, 0, stream>>>(ea, consts, E);
    k_nodes<<<nbl, 256, 0, stream>>>(x, consts, xs8, a_d, N);
    k_bstart<<<nbl, 256, 0, stream>>>(pool_batch, bstart, N, B);
    k_p1<<<(E + TILE - 1) / TILE, 256, 0, stream>>>(src, dst, ea, consts, slab, gcur, E, R, CAP);
    dim3 g2grid(S, R);
    k_p2<<<g2grid, 256, 0, stream>>>(slab, gcur, xs8, a_d, partials, S, CAP, N);
    k_p3<<<nbl, 256, 0, stream>>>(partials, xs8, a_d, consts, y, N, S, inv_E);
    k_pool<<<2 * B, 128, 0, stream>>>(y, consts, bstart, g2, B);
    k_head<<<B, 128, 0, stream>>>(g2, bstart, agent, W_fc2, b_fc2, W_v1, b_v1, W_v2, b_v2,
                                  W_a1, b_a1, W_a2, b_a2, (float*)d_out, A, B);
}

// Round 5
// 168.808 us; speedup vs baseline: 6.4250x; 1.4812x over previous
//
#include <hip/hip_runtime.h>
#include <math.h>

#define NPB   512      // nodes per bucket (N=102400 = 200*512 exactly)
#define NPBL  9
#define MAXR  256      // max buckets
#define TILE  2048     // edges per k_p1 block
#define RPT   8        // records per thread in k_p1
#define GCS   16       // gcur stride in u32 (64B line padding)
#define EPARTS 256     // easum partial count

static __device__ __forceinline__ float lrelu(float x) { return x > 0.0f ? x : 0.2f * x; }

// consts layout (floats):
// [0] sum_ea, [1] c_edge, [2..6] va, [7..11] vd, [16..143] bc, [144..783] Wc[5][128]

// ---- stage 1: grid-stride partial sums of edge_attr (no same-address atomics) ----
__global__ void k_easum_part(const float* __restrict__ ea, float* __restrict__ part, int n) {
    __shared__ float s[256];
    int t = threadIdx.x;
    int n4 = n >> 2;
    const float4* ea4 = (const float4*)ea;
    float acc = 0.f;
    for (int i = blockIdx.x * 256 + t; i < n4; i += EPARTS * 256) {
        float4 v = ea4[i];
        acc += v.x + v.y + v.z + v.w;
    }
    // tail (n not multiple of 4)
    if (blockIdx.x == 0 && t < (n & 3)) acc += ea[n4 * 4 + t];
    s[t] = acc;
    __syncthreads();
    for (int o = 128; o > 0; o >>= 1) {
        if (t < o) s[t] += s[t + o];
        __syncthreads();
    }
    if (t == 0) part[blockIdx.x] = s[0];
}

// ---- setup: fold weights + finalize easum ----
__global__ void k_setup(const float* __restrict__ W_gat, const float* __restrict__ att_src,
                        const float* __restrict__ att_dst, const float* __restrict__ W_edge,
                        const float* __restrict__ att_edge, const float* __restrict__ b_gat,
                        const float* __restrict__ W_fc1, const float* __restrict__ b_fc1,
                        const float* __restrict__ part, float* __restrict__ consts) {
    __shared__ float s[128];
    int t = threadIdx.x;  // 128 threads
    s[t] = part[t] + part[t + 128];
    __syncthreads();
    for (int o = 64; o > 0; o >>= 1) {
        if (t < o) s[t] += s[t + o];
        __syncthreads();
    }
    if (t == 0) consts[0] = s[0];
    if (t == 0) {
        float c = 0.f;
        for (int k = 0; k < 64; k++) c += W_edge[k] * att_edge[k];
        consts[1] = c;
    }
    if (t < 5) {
        float a = 0.f, b = 0.f;
        for (int c = 0; c < 64; c++) {
            float w = W_gat[t * 64 + c];
            a += w * att_src[c];
            b += w * att_dst[c];
        }
        consts[2 + t] = a;
        consts[7 + t] = b;
    }
    float bcv = b_fc1[t];
    for (int c = 0; c < 64; c++) bcv += b_gat[c] * W_fc1[c * 128 + t];
    consts[16 + t] = bcv;
    for (int k = 0; k < 5; k++) {
        float w = 0.f;
        for (int c = 0; c < 64; c++) w += W_gat[k * 64 + c] * W_fc1[c * 128 + t];
        consts[144 + k * 128 + t] = w;
    }
}

// per-node: xs8 = {x0..x4, a_s, 0, 0} (32B struct), a_d separate; fused bstart
__global__ void k_nodes(const float* __restrict__ x, const float* __restrict__ consts,
                        float* __restrict__ xs8, float* __restrict__ a_d,
                        const int* __restrict__ pb, int* __restrict__ bstart, int n, int B) {
    int i = blockIdx.x * blockDim.x + threadIdx.x;
    if (i >= n) return;
    const float* xi = x + (size_t)i * 5;
    float x0 = xi[0], x1 = xi[1], x2 = xi[2], x3 = xi[3], x4 = xi[4];
    float as = x0 * consts[2] + x1 * consts[3] + x2 * consts[4] + x3 * consts[5] + x4 * consts[6];
    float ad = x0 * consts[7] + x1 * consts[8] + x2 * consts[9] + x3 * consts[10] + x4 * consts[11];
    float* o = xs8 + (size_t)i * 8;
    o[0] = x0; o[1] = x1; o[2] = x2; o[3] = x3; o[4] = x4;
    o[5] = as; o[6] = 0.f; o[7] = 0.f;
    a_d[i] = ad;
    int cur = pb[i];
    int prev = (i == 0) ? -1 : pb[i - 1];
    for (int b = prev + 1; b <= cur; b++) bstart[b] = i;
    if (i == n - 1)
        for (int b = cur + 1; b <= B; b++) bstart[b] = n;
}

// ---- phase 1: bin edges by dst bucket; LDS counting sort -> coalesced slab flush ----
// record: {u32 (src<<9)|dstLocal, f32 c_edge*ea[e]}
__global__ void k_p1(const int* __restrict__ src, const int* __restrict__ dst,
                     const float* __restrict__ ea, const float* __restrict__ consts,
                     uint2* __restrict__ slab, unsigned* __restrict__ gcur,
                     int E, int R, int CAP) {
    __shared__ unsigned hist[MAXR], lbase[MAXR], gbase[MAXR], scan[256];
    __shared__ uint2 staged[TILE];
    __shared__ unsigned char bof[TILE];
    int t = threadIdx.x;  // 256
    int e0 = blockIdx.x * TILE;
    int n = E - e0; if (n > TILE) n = TILE;
    for (int i = t; i < MAXR; i += 256) hist[i] = 0;
    __syncthreads();
    unsigned key[RPT]; float val[RPT]; unsigned brk[RPT];
    float ce = consts[1];
#pragma unroll
    for (int k = 0; k < RPT; k++) {
        int idx = t + k * 256;
        brk[k] = 0xFFFFFFFFu;
        if (idx < n) {
            int e = e0 + idx;
            int d = dst[e];
            unsigned b = (unsigned)d >> NPBL;
            key[k] = ((unsigned)src[e] << NPBL) | ((unsigned)d & (NPB - 1));
            val[k] = ce * ea[e];
            unsigned r = atomicAdd(&hist[b], 1u);
            brk[k] = (b << 12) | r;
        }
    }
    __syncthreads();
    unsigned v = (t < R) ? hist[t] : 0;
    if (t < R) gbase[t] = atomicAdd(&gcur[t * GCS], v);
    scan[t] = v;
    __syncthreads();
    for (int off = 1; off < 256; off <<= 1) {
        unsigned add = (t >= off) ? scan[t - off] : 0;
        __syncthreads();
        scan[t] += add;
        __syncthreads();
    }
    if (t < R) lbase[t] = scan[t] - v;
    __syncthreads();
#pragma unroll
    for (int k = 0; k < RPT; k++) {
        if (brk[k] != 0xFFFFFFFFu) {
            unsigned b = brk[k] >> 12, r = brk[k] & 4095u;
            unsigned pos = lbase[b] + r;
            staged[pos] = make_uint2(key[k], __float_as_uint(val[k]));
            bof[pos] = (unsigned char)b;
        }
    }
    __syncthreads();
    for (int i = t; i < n; i += 256) {
        unsigned b = bof[i];
        unsigned slot = gbase[b] + (unsigned)i - lbase[b];
        if (slot < (unsigned)CAP) slab[(size_t)b * CAP + slot] = staged[i];
    }
}

// ---- phase 2: per (slice s, bucket r): small-LDS aggregation, high occupancy ----
__global__ void k_p2(const uint2* __restrict__ slab, const unsigned* __restrict__ gcur,
                     const float* __restrict__ xs8, const float* __restrict__ a_d,
                     float* __restrict__ partials, int S, int CAP, int N) {
    __shared__ float acc[NPB * 6];   // 12.3 KB
    __shared__ float adl[NPB];       // 2 KB
    int t = threadIdx.x;  // 256
    int s = blockIdx.x, r = blockIdx.y;
    for (int i = t; i < NPB * 6; i += 256) acc[i] = 0.f;
    for (int i = t; i < NPB; i += 256) {
        int node = r * NPB + i;
        adl[i] = (node < N) ? a_d[node] : 0.f;
    }
    __syncthreads();
    unsigned cnt = gcur[r * GCS]; if (cnt > (unsigned)CAP) cnt = CAP;
    unsigned L = (cnt + (unsigned)S - 1) / (unsigned)S;
    unsigned i0 = (unsigned)s * L, i1 = i0 + L; if (i1 > cnt) i1 = cnt;
    const uint2* sl = slab + (size_t)r * CAP;
    for (unsigned i = i0 + t; i < i1; i += 256) {
        uint2 rec = sl[i];
        unsigned dl = rec.x & (NPB - 1);
        unsigned sr = rec.x >> NPBL;
        const float* xp = xs8 + (size_t)sr * 8;   // one 64B-line gather
        float al = lrelu(xp[5] + adl[dl] + __uint_as_float(rec.y));
        float ex = __expf(al);
        float* a = acc + dl * 6;
        atomicAdd(a + 0, ex * xp[0]);
        atomicAdd(a + 1, ex * xp[1]);
        atomicAdd(a + 2, ex * xp[2]);
        atomicAdd(a + 3, ex * xp[3]);
        atomicAdd(a + 4, ex * xp[4]);
        atomicAdd(a + 5, ex);
    }
    __syncthreads();
    float* out = partials + (size_t)(r * S + s) * (NPB * 6);
    for (int i = t; i < NPB * 6; i += 256) out[i] = acc[i];
}

// ---- phase 3: merge S partials + self-loop, normalize -> y[N][5] ----
__global__ void k_p3(const float* __restrict__ partials, const float* __restrict__ xs8,
                     const float* __restrict__ a_d, const float* __restrict__ consts,
                     float* __restrict__ y, int N, int S, float inv_E) {
    int i = blockIdx.x * blockDim.x + threadIdx.x;
    if (i >= N) return;
    int r = i >> NPBL, dl = i & (NPB - 1);
    float y0 = 0, y1 = 0, y2 = 0, y3 = 0, y4 = 0, ss = 0;
    const float* p = partials + (size_t)r * S * (NPB * 6) + (size_t)dl * 6;
    for (int s = 0; s < S; s++) {
        const float* q = p + (size_t)s * (NPB * 6);
        y0 += q[0]; y1 += q[1]; y2 += q[2]; y3 += q[3]; y4 += q[4]; ss += q[5];
    }
    const float* xp = xs8 + (size_t)i * 8;
    float mean_ea = consts[0] * inv_E;
    float aself = lrelu(xp[5] + a_d[i] + consts[1] * mean_ea);
    float exs = __expf(aself);
    float inv = 1.f / (ss + exs + 1e-16f);
    y[(size_t)i * 5 + 0] = (y0 + exs * xp[0]) * inv;
    y[(size_t)i * 5 + 1] = (y1 + exs * xp[1]) * inv;
    y[(size_t)i * 5 + 2] = (y2 + exs * xp[2]) * inv;
    y[(size_t)i * 5 + 3] = (y3 + exs * xp[3]) * inv;
    y[(size_t)i * 5 + 4] = (y4 + exs * xp[4]) * inv;
}

// ---- pool: 2 blocks per batch, register accumulate, direct store (no atomics) ----
__global__ void k_pool(const float* __restrict__ y, const float* __restrict__ consts,
                       const int* __restrict__ bstart, float* __restrict__ g2, int B) {
    int l = threadIdx.x;  // 128 threads
    int b = blockIdx.x >> 1, half = blockIdx.x & 1;
    int st = bstart[b], en = bstart[b + 1];
    int len = en - st;
    int h0 = (len + 1) >> 1;
    int i0 = half ? st + h0 : st;
    int i1 = half ? en : st + h0;
    float w0 = consts[144 + l], w1 = consts[272 + l], w2 = consts[400 + l],
          w3 = consts[528 + l], w4 = consts[656 + l];
    float bc = consts[16 + l];
    float accum = 0.f;
    for (int i = i0; i < i1; ++i) {
        const float* yi = y + (size_t)i * 5;
        float h = bc + yi[0] * w0 + yi[1] * w1 + yi[2] * w2 + yi[3] * w3 + yi[4] * w4;
        accum += fmaxf(h, 0.f);
    }
    g2[((size_t)half * B + b) * 128 + l] = accum;
}

// ---- head MLP: one block per batch row ----
__global__ void k_head(const float* __restrict__ g2, const int* __restrict__ bstart,
                       const float* __restrict__ agent_state, const float* __restrict__ W_fc2,
                       const float* __restrict__ b_fc2, const float* __restrict__ W_v1,
                       const float* __restrict__ b_v1, const float* __restrict__ W_v2,
                       const float* __restrict__ b_v2, const float* __restrict__ W_a1,
                       const float* __restrict__ b_a1, const float* __restrict__ W_a2,
                       const float* __restrict__ b_a2, float* __restrict__ out, int A, int B) {
    __shared__ float z[192];
    __shared__ float v1s[128], a1s[128], red[128];
    __shared__ float advs[8];
    int b = blockIdx.x, t = threadIdx.x;  // 128 threads
    float cnt = (float)(bstart[b + 1] - bstart[b]);
    cnt = cnt < 1.f ? 1.f : cnt;
    z[t] = (g2[(size_t)b * 128 + t] + g2[((size_t)B + b) * 128 + t]) / cnt;
    if (t < 64) {
        float a = b_fc2[t];
        const float* as_ = agent_state + b * 34;
        for (int k = 0; k < 34; k++) a += as_[k] * W_fc2[k * 64 + t];
        z[128 + t] = fmaxf(a, 0.f);
    }
    __syncthreads();
    float v = b_v1[t], a = b_a1[t];
    for (int j = 0; j < 192; j++) {
        float zj = z[j];
        v += zj * W_v1[j * 128 + t];
        a += zj * W_a1[j * 128 + t];
    }
    v1s[t] = fmaxf(v, 0.f);
    a1s[t] = fmaxf(a, 0.f);
    __syncthreads();
    red[t] = v1s[t] * W_v2[t];
    __syncthreads();
    for (int o = 64; o > 0; o >>= 1) {
        if (t < o) red[t] += red[t + o];
        __syncthreads();
    }
    float value = red[0] + b_v2[0];
    if (t < A) {
        float ad = b_a2[t];
        for (int j = 0; j < 128; j++) ad += a1s[j] * W_a2[j * A + t];
        advs[t] = ad;
    }
    __syncthreads();
    if (t == 0) {
        float m = 0.f;
        for (int j = 0; j < A; j++) m += advs[j];
        m *= (1.f / (float)A);
        for (int j = 0; j < A; j++) out[b * A + j] = value + advs[j] - m;
    }
}

extern "C" void kernel_launch(void* const* d_in, const int* in_sizes, int n_in,
                              void* d_out, int out_size, void* d_ws, size_t ws_size,
                              hipStream_t stream) {
    const float* x        = (const float*)d_in[0];
    const int* edge_index = (const int*)d_in[1];
    const float* ea       = (const float*)d_in[2];
    const float* agent    = (const float*)d_in[3];
    const int* pool_batch = (const int*)d_in[4];
    const float* W_gat    = (const float*)d_in[5];
    const float* att_src  = (const float*)d_in[6];
    const float* att_dst  = (const float*)d_in[7];
    const float* W_edge   = (const float*)d_in[8];
    const float* att_edge = (const float*)d_in[9];
    const float* b_gat    = (const float*)d_in[10];
    const float* W_fc1    = (const float*)d_in[11];
    const float* b_fc1    = (const float*)d_in[12];
    const float* W_fc2    = (const float*)d_in[13];
    const float* b_fc2    = (const float*)d_in[14];
    const float* W_v1     = (const float*)d_in[15];
    const float* b_v1     = (const float*)d_in[16];
    const float* W_v2     = (const float*)d_in[17];
    const float* b_v2     = (const float*)d_in[18];
    const float* W_a1     = (const float*)d_in[19];
    const float* b_a1     = (const float*)d_in[20];
    const float* W_a2     = (const float*)d_in[21];
    const float* b_a2     = (const float*)d_in[22];

    const int N = in_sizes[0] / 5;
    const int E = in_sizes[2];
    const int B = in_sizes[3] / 34;
    const int A = out_size / B;
    const float inv_E = 1.0f / (float)E;

    const int* src = edge_index;
    const int* dst = edge_index + E;

    const int R = (N + NPB - 1) / NPB;            // 200 buckets
    int capBase = (E + R - 1) / R;                // ~8192
    const int CAP = capBase + capBase / 16 + 256;

    // ---- ws layout ----
    char* ws = (char*)d_ws;
    size_t off = 0;
    auto take = [&](size_t bytes) {
        size_t o = off;
        off = (off + bytes + 255) & ~(size_t)255;
        return o;
    };
    size_t o_consts = take(4096);                       // zeroed
    size_t o_gcur   = take((size_t)MAXR * GCS * 4);     // zeroed (64B-padded counters)
    size_t zero_bytes = off;
    size_t o_epart  = take((size_t)EPARTS * 4);
    size_t o_xs8    = take((size_t)N * 8 * 4);
    size_t o_ad     = take((size_t)N * 4);
    size_t o_y      = take((size_t)N * 5 * 4);
    size_t o_bstart = take((size_t)(B + 1) * 4);
    size_t o_g2     = take((size_t)2 * B * 128 * 4);
    size_t o_slab   = take((size_t)R * CAP * 8);
    size_t o_part   = off;
    size_t perS = (size_t)R * NPB * 6 * 4;
    int S = 8;
    while (S > 1 && o_part + (size_t)S * perS > ws_size) S--;

    float* consts   = (float*)(ws + o_consts);
    unsigned* gcur  = (unsigned*)(ws + o_gcur);
    float* epart    = (float*)(ws + o_epart);
    float* xs8      = (float*)(ws + o_xs8);
    float* a_d      = (float*)(ws + o_ad);
    float* y        = (float*)(ws + o_y);
    int* bstart     = (int*)(ws + o_bstart);
    float* g2       = (float*)(ws + o_g2);
    uint2* slab     = (uint2*)(ws + o_slab);
    float* partials = (float*)(ws + o_part);

    hipMemsetAsync(d_ws, 0, zero_bytes, stream);

    k_easum_part<<<EPARTS, 256, 0, stream>>>(ea, epart, E);
    k_setup<<<1, 128, 0, stream>>>(W_gat, att_src, att_dst, W_edge, att_edge, b_gat,
                                   W_fc1, b_fc1, epart, consts);

    int nbl = (N + 255) / 256;
    k_nodes<<<nbl, 256, 0, stream>>>(x, consts, xs8, a_d, pool_batch, bstart, N, B);
    k_p1<<<(E + TILE - 1) / TILE, 256, 0, stream>>>(src, dst, ea, consts, slab, gcur, E, R, CAP);
    dim3 g2grid(S, R);
    k_p2<<<g2grid, 256, 0, stream>>>(slab, gcur, xs8, a_d, partials, S, CAP, N);
    k_p3<<<nbl, 256, 0, stream>>>(partials, xs8, a_d, consts, y, N, S, inv_E);
    k_pool<<<2 * B, 128, 0, stream>>>(y, consts, bstart, g2, B);
    k_head<<<B, 128, 0, stream>>>(g2, bstart, agent, W_fc2, b_fc2, W_v1, b_v1, W_v2, b_v2,
                                  W_a1, b_a1, W_a2, b_a2, (float*)d_out, A, B);
}

// Round 6
// 162.145 us; speedup vs baseline: 6.6891x; 1.0411x over previous
//
#include <hip/hip_runtime.h>
#include <math.h>

#define NPB   512      // nodes per bucket (N=102400 = 200*512 exactly)
#define NPBL  9
#define MAXR  256      // max buckets
#define TILE  2048     // edges per k_p1 block
#define RPT   8        // records per thread in k_p1
#define GCS   16       // gcur stride in u32 (64B line padding)
#define EPARTS 256     // easum partial count

static __device__ __forceinline__ float lrelu(float x) { return x > 0.0f ? x : 0.2f * x; }

// consts layout (floats):
// [0] sum_ea, [1] c_edge, [2..6] va, [7..11] vd, [16..143] bc, [144..783] Wc[5][128]

// ---- stage 1: grid-stride partial sums of edge_attr ----
__global__ void k_easum_part(const float* __restrict__ ea, float* __restrict__ part, int n) {
    __shared__ float s[256];
    int t = threadIdx.x;
    int n4 = n >> 2;
    const float4* ea4 = (const float4*)ea;
    float acc = 0.f;
    for (int i = blockIdx.x * 256 + t; i < n4; i += EPARTS * 256) {
        float4 v = ea4[i];
        acc += v.x + v.y + v.z + v.w;
    }
    if (blockIdx.x == 0 && t < (n & 3)) acc += ea[n4 * 4 + t];
    s[t] = acc;
    __syncthreads();
    for (int o = 128; o > 0; o >>= 1) {
        if (t < o) s[t] += s[t + o];
        __syncthreads();
    }
    if (t == 0) part[blockIdx.x] = s[0];
}

// ---- setup: fold weights + finalize easum ----
__global__ void k_setup(const float* __restrict__ W_gat, const float* __restrict__ att_src,
                        const float* __restrict__ att_dst, const float* __restrict__ W_edge,
                        const float* __restrict__ att_edge, const float* __restrict__ b_gat,
                        const float* __restrict__ W_fc1, const float* __restrict__ b_fc1,
                        const float* __restrict__ part, float* __restrict__ consts) {
    __shared__ float s[128];
    int t = threadIdx.x;  // 128 threads
    s[t] = part[t] + part[t + 128];
    __syncthreads();
    for (int o = 64; o > 0; o >>= 1) {
        if (t < o) s[t] += s[t + o];
        __syncthreads();
    }
    if (t == 0) consts[0] = s[0];
    if (t == 0) {
        float c = 0.f;
        for (int k = 0; k < 64; k++) c += W_edge[k] * att_edge[k];
        consts[1] = c;
    }
    if (t < 5) {
        float a = 0.f, b = 0.f;
        for (int c = 0; c < 64; c++) {
            float w = W_gat[t * 64 + c];
            a += w * att_src[c];
            b += w * att_dst[c];
        }
        consts[2 + t] = a;
        consts[7 + t] = b;
    }
    float bcv = b_fc1[t];
    for (int c = 0; c < 64; c++) bcv += b_gat[c] * W_fc1[c * 128 + t];
    consts[16 + t] = bcv;
    for (int k = 0; k < 5; k++) {
        float w = 0.f;
        for (int c = 0; c < 64; c++) w += W_gat[k * 64 + c] * W_fc1[c * 128 + t];
        consts[144 + k * 128 + t] = w;
    }
}

// per-node: xs8 = {x0..x4, a_s, 0, 0} (32B struct, float4-stored), a_d separate; fused bstart
__global__ void k_nodes(const float* __restrict__ x, const float* __restrict__ consts,
                        float* __restrict__ xs8, float* __restrict__ a_d,
                        const int* __restrict__ pb, int* __restrict__ bstart, int n, int B) {
    int i = blockIdx.x * blockDim.x + threadIdx.x;
    if (i >= n) return;
    const float* xi = x + (size_t)i * 5;
    float x0 = xi[0], x1 = xi[1], x2 = xi[2], x3 = xi[3], x4 = xi[4];
    float as = x0 * consts[2] + x1 * consts[3] + x2 * consts[4] + x3 * consts[5] + x4 * consts[6];
    float ad = x0 * consts[7] + x1 * consts[8] + x2 * consts[9] + x3 * consts[10] + x4 * consts[11];
    float4* o = (float4*)(xs8 + (size_t)i * 8);
    o[0] = make_float4(x0, x1, x2, x3);
    o[1] = make_float4(x4, as, 0.f, 0.f);
    a_d[i] = ad;
    int cur = pb[i];
    int prev = (i == 0) ? -1 : pb[i - 1];
    for (int b = prev + 1; b <= cur; b++) bstart[b] = i;
    if (i == n - 1)
        for (int b = cur + 1; b <= B; b++) bstart[b] = n;
}

// ---- phase 1: bin edges by dst bucket; LDS counting sort -> coalesced slab flush ----
// record: {u32 (src<<9)|dstLocal, f32 c_edge*ea[e]}
__global__ void k_p1(const int* __restrict__ src, const int* __restrict__ dst,
                     const float* __restrict__ ea, const float* __restrict__ consts,
                     uint2* __restrict__ slab, unsigned* __restrict__ gcur,
                     int E, int R, int CAP) {
    __shared__ unsigned hist[MAXR], lbase[MAXR], gbase[MAXR], scan[256];
    __shared__ uint2 staged[TILE];
    __shared__ unsigned char bof[TILE];
    int t = threadIdx.x;  // 256
    int e0 = blockIdx.x * TILE;
    int n = E - e0; if (n > TILE) n = TILE;
    for (int i = t; i < MAXR; i += 256) hist[i] = 0;
    __syncthreads();
    unsigned key[RPT]; float val[RPT]; unsigned brk[RPT];
    float ce = consts[1];
#pragma unroll
    for (int k = 0; k < RPT; k++) {
        int idx = t + k * 256;
        brk[k] = 0xFFFFFFFFu;
        if (idx < n) {
            int e = e0 + idx;
            int d = dst[e];
            unsigned b = (unsigned)d >> NPBL;
            key[k] = ((unsigned)src[e] << NPBL) | ((unsigned)d & (NPB - 1));
            val[k] = ce * ea[e];
            unsigned r = atomicAdd(&hist[b], 1u);
            brk[k] = (b << 12) | r;
        }
    }
    __syncthreads();
    unsigned v = (t < R) ? hist[t] : 0;
    if (t < R) gbase[t] = atomicAdd(&gcur[t * GCS], v);
    scan[t] = v;
    __syncthreads();
    for (int off = 1; off < 256; off <<= 1) {
        unsigned add = (t >= off) ? scan[t - off] : 0;
        __syncthreads();
        scan[t] += add;
        __syncthreads();
    }
    if (t < R) lbase[t] = scan[t] - v;
    __syncthreads();
#pragma unroll
    for (int k = 0; k < RPT; k++) {
        if (brk[k] != 0xFFFFFFFFu) {
            unsigned b = brk[k] >> 12, r = brk[k] & 4095u;
            unsigned pos = lbase[b] + r;
            staged[pos] = make_uint2(key[k], __float_as_uint(val[k]));
            bof[pos] = (unsigned char)b;
        }
    }
    __syncthreads();
    for (int i = t; i < n; i += 256) {
        unsigned b = bof[i];
        unsigned slot = gbase[b] + (unsigned)i - lbase[b];
        if (slot < (unsigned)CAP) slab[(size_t)b * CAP + slot] = staged[i];
    }
}

// ---- phase 2: per (slice s, bucket r): LDS aggregation; float4 gathers, 4-deep pipeline ----
// partials layout (SoA): [r][s][6][NPB]
__global__ void k_p2(const uint2* __restrict__ slab, const unsigned* __restrict__ gcur,
                     const float* __restrict__ xs8, const float* __restrict__ a_d,
                     float* __restrict__ partials, int S, int CAP, int N) {
    __shared__ float acc[NPB * 6];   // 12.3 KB
    __shared__ float adl[NPB];       // 2 KB
    int t = threadIdx.x;  // 256
    int s = blockIdx.x, r = blockIdx.y;
    for (int i = t; i < NPB * 6; i += 256) acc[i] = 0.f;
    for (int i = t; i < NPB; i += 256) {
        int node = r * NPB + i;
        adl[i] = (node < N) ? a_d[node] : 0.f;
    }
    __syncthreads();
    unsigned cnt = gcur[r * GCS]; if (cnt > (unsigned)CAP) cnt = CAP;
    unsigned L = (cnt + (unsigned)S - 1) / (unsigned)S;
    unsigned i0 = (unsigned)s * L, i1 = i0 + L; if (i1 > cnt) i1 = cnt;
    const uint2* sl = slab + (size_t)r * CAP;
    unsigned i = i0 + t;
    for (; i + 768 < i1; i += 1024) {
        uint2 r0 = sl[i], r1 = sl[i + 256], r2 = sl[i + 512], r3 = sl[i + 768];
        const float4* p0 = (const float4*)(xs8 + (size_t)(r0.x >> NPBL) * 8);
        const float4* p1 = (const float4*)(xs8 + (size_t)(r1.x >> NPBL) * 8);
        const float4* p2 = (const float4*)(xs8 + (size_t)(r2.x >> NPBL) * 8);
        const float4* p3 = (const float4*)(xs8 + (size_t)(r3.x >> NPBL) * 8);
        float4 lo0 = p0[0], hi0 = p0[1];
        float4 lo1 = p1[0], hi1 = p1[1];
        float4 lo2 = p2[0], hi2 = p2[1];
        float4 lo3 = p3[0], hi3 = p3[1];
#define DO_REC(rr, lo, hi) { \
        unsigned dl = rr.x & (NPB - 1); \
        float ex = __expf(lrelu(hi.y + adl[dl] + __uint_as_float(rr.y))); \
        float* a = acc + dl * 6; \
        atomicAdd(a + 0, ex * lo.x); \
        atomicAdd(a + 1, ex * lo.y); \
        atomicAdd(a + 2, ex * lo.z); \
        atomicAdd(a + 3, ex * lo.w); \
        atomicAdd(a + 4, ex * hi.x); \
        atomicAdd(a + 5, ex); }
        DO_REC(r0, lo0, hi0)
        DO_REC(r1, lo1, hi1)
        DO_REC(r2, lo2, hi2)
        DO_REC(r3, lo3, hi3)
    }
    for (; i < i1; i += 256) {
        uint2 r0 = sl[i];
        const float4* p0 = (const float4*)(xs8 + (size_t)(r0.x >> NPBL) * 8);
        float4 lo0 = p0[0], hi0 = p0[1];
        DO_REC(r0, lo0, hi0)
    }
#undef DO_REC
    __syncthreads();
    // SoA transpose writeout: out[comp*NPB + dl] = acc[dl*6 + comp]
    float* out = partials + (size_t)(r * S + s) * (NPB * 6);
    for (int j = t; j < NPB * 6; j += 256) {
        int comp = j >> NPBL, dl = j & (NPB - 1);
        out[j] = acc[dl * 6 + comp];
    }
}

// ---- phase 3: merge S partials + self-loop, normalize -> y SoA [5][N] ----
__global__ void k_p3(const float* __restrict__ partials, const float* __restrict__ xs8,
                     const float* __restrict__ a_d, const float* __restrict__ consts,
                     float* __restrict__ y, int N, int S, float inv_E) {
    int i = blockIdx.x * blockDim.x + threadIdx.x;
    if (i >= N) return;
    int r = i >> NPBL, dl = i & (NPB - 1);
    float y0 = 0, y1 = 0, y2 = 0, y3 = 0, y4 = 0, ss = 0;
    const float* p = partials + (size_t)r * S * (NPB * 6) + dl;
    for (int s = 0; s < S; s++) {
        const float* q = p + (size_t)s * (NPB * 6);
        y0 += q[0 * NPB]; y1 += q[1 * NPB]; y2 += q[2 * NPB];
        y3 += q[3 * NPB]; y4 += q[4 * NPB]; ss += q[5 * NPB];
    }
    const float4* xp = (const float4*)(xs8 + (size_t)i * 8);
    float4 lo = xp[0], hi = xp[1];
    float mean_ea = consts[0] * inv_E;
    float aself = lrelu(hi.y + a_d[i] + consts[1] * mean_ea);
    float exs = __expf(aself);
    float inv = 1.f / (ss + exs + 1e-16f);
    y[0 * (size_t)N + i] = (y0 + exs * lo.x) * inv;
    y[1 * (size_t)N + i] = (y1 + exs * lo.y) * inv;
    y[2 * (size_t)N + i] = (y2 + exs * lo.z) * inv;
    y[3 * (size_t)N + i] = (y3 + exs * lo.w) * inv;
    y[4 * (size_t)N + i] = (y4 + exs * hi.x) * inv;
}

// ---- pool: 2 blocks per batch, register accumulate, direct store (no atomics) ----
__global__ void k_pool(const float* __restrict__ y, const float* __restrict__ consts,
                       const int* __restrict__ bstart, float* __restrict__ g2, int B, int N) {
    int l = threadIdx.x;  // 128 threads
    int b = blockIdx.x >> 1, half = blockIdx.x & 1;
    int st = bstart[b], en = bstart[b + 1];
    int len = en - st;
    int h0 = (len + 1) >> 1;
    int i0 = half ? st + h0 : st;
    int i1 = half ? en : st + h0;
    float w0 = consts[144 + l], w1 = consts[272 + l], w2 = consts[400 + l],
          w3 = consts[528 + l], w4 = consts[656 + l];
    float bc = consts[16 + l];
    const float* y0 = y;
    const float* y1p = y + (size_t)N;
    const float* y2p = y + 2 * (size_t)N;
    const float* y3p = y + 3 * (size_t)N;
    const float* y4p = y + 4 * (size_t)N;
    float accum = 0.f;
    for (int i = i0; i < i1; ++i) {
        float h = bc + y0[i] * w0 + y1p[i] * w1 + y2p[i] * w2 + y3p[i] * w3 + y4p[i] * w4;
        accum += fmaxf(h, 0.f);
    }
    g2[((size_t)half * B + b) * 128 + l] = accum;
}

// ---- head MLP: one block per batch row ----
__global__ void k_head(const float* __restrict__ g2, const int* __restrict__ bstart,
                       const float* __restrict__ agent_state, const float* __restrict__ W_fc2,
                       const float* __restrict__ b_fc2, const float* __restrict__ W_v1,
                       const float* __restrict__ b_v1, const float* __restrict__ W_v2,
                       const float* __restrict__ b_v2, const float* __restrict__ W_a1,
                       const float* __restrict__ b_a1, const float* __restrict__ W_a2,
                       const float* __restrict__ b_a2, float* __restrict__ out, int A, int B) {
    __shared__ float z[192];
    __shared__ float v1s[128], a1s[128], red[128];
    __shared__ float advs[8];
    int b = blockIdx.x, t = threadIdx.x;  // 128 threads
    float cnt = (float)(bstart[b + 1] - bstart[b]);
    cnt = cnt < 1.f ? 1.f : cnt;
    z[t] = (g2[(size_t)b * 128 + t] + g2[((size_t)B + b) * 128 + t]) / cnt;
    if (t < 64) {
        float a = b_fc2[t];
        const float* as_ = agent_state + b * 34;
        for (int k = 0; k < 34; k++) a += as_[k] * W_fc2[k * 64 + t];
        z[128 + t] = fmaxf(a, 0.f);
    }
    __syncthreads();
    float v = b_v1[t], a = b_a1[t];
    for (int j = 0; j < 192; j++) {
        float zj = z[j];
        v += zj * W_v1[j * 128 + t];
        a += zj * W_a1[j * 128 + t];
    }
    v1s[t] = fmaxf(v, 0.f);
    a1s[t] = fmaxf(a, 0.f);
    __syncthreads();
    red[t] = v1s[t] * W_v2[t];
    __syncthreads();
    for (int o = 64; o > 0; o >>= 1) {
        if (t < o) red[t] += red[t + o];
        __syncthreads();
    }
    float value = red[0] + b_v2[0];
    if (t < A) {
        float ad = b_a2[t];
        for (int j = 0; j < 128; j++) ad += a1s[j] * W_a2[j * A + t];
        advs[t] = ad;
    }
    __syncthreads();
    if (t == 0) {
        float m = 0.f;
        for (int j = 0; j < A; j++) m += advs[j];
        m *= (1.f / (float)A);
        for (int j = 0; j < A; j++) out[b * A + j] = value + advs[j] - m;
    }
}

extern "C" void kernel_launch(void* const* d_in, const int* in_sizes, int n_in,
                              void* d_out, int out_size, void* d_ws, size_t ws_size,
                              hipStream_t stream) {
    const float* x        = (const float*)d_in[0];
    const int* edge_index = (const int*)d_in[1];
    const float* ea       = (const float*)d_in[2];
    const float* agent    = (const float*)d_in[3];
    const int* pool_batch = (const int*)d_in[4];
    const float* W_gat    = (const float*)d_in[5];
    const float* att_src  = (const float*)d_in[6];
    const float* att_dst  = (const float*)d_in[7];
    const float* W_edge   = (const float*)d_in[8];
    const float* att_edge = (const float*)d_in[9];
    const float* b_gat    = (const float*)d_in[10];
    const float* W_fc1    = (const float*)d_in[11];
    const float* b_fc1    = (const float*)d_in[12];
    const float* W_fc2    = (const float*)d_in[13];
    const float* b_fc2    = (const float*)d_in[14];
    const float* W_v1     = (const float*)d_in[15];
    const float* b_v1     = (const float*)d_in[16];
    const float* W_v2     = (const float*)d_in[17];
    const float* b_v2     = (const float*)d_in[18];
    const float* W_a1     = (const float*)d_in[19];
    const float* b_a1     = (const float*)d_in[20];
    const float* W_a2     = (const float*)d_in[21];
    const float* b_a2     = (const float*)d_in[22];

    const int N = in_sizes[0] / 5;
    const int E = in_sizes[2];
    const int B = in_sizes[3] / 34;
    const int A = out_size / B;
    const float inv_E = 1.0f / (float)E;

    const int* src = edge_index;
    const int* dst = edge_index + E;

    const int R = (N + NPB - 1) / NPB;            // 200 buckets
    int capBase = (E + R - 1) / R;                // ~8192
    const int CAP = capBase + capBase / 16 + 256;

    // ---- ws layout ----
    char* ws = (char*)d_ws;
    size_t off = 0;
    auto take = [&](size_t bytes) {
        size_t o = off;
        off = (off + bytes + 255) & ~(size_t)255;
        return o;
    };
    size_t o_consts = take(4096);                       // zeroed
    size_t o_gcur   = take((size_t)MAXR * GCS * 4);     // zeroed (64B-padded counters)
    size_t zero_bytes = off;
    size_t o_epart  = take((size_t)EPARTS * 4);
    size_t o_xs8    = take((size_t)N * 8 * 4);
    size_t o_ad     = take((size_t)N * 4);
    size_t o_y      = take((size_t)N * 5 * 4);
    size_t o_bstart = take((size_t)(B + 1) * 4);
    size_t o_g2     = take((size_t)2 * B * 128 * 4);
    size_t o_slab   = take((size_t)R * CAP * 8);
    size_t o_part   = off;
    size_t perS = (size_t)R * NPB * 6 * 4;
    int S = 8;
    while (S > 1 && o_part + (size_t)S * perS > ws_size) S--;

    float* consts   = (float*)(ws + o_consts);
    unsigned* gcur  = (unsigned*)(ws + o_gcur);
    float* epart    = (float*)(ws + o_epart);
    float* xs8      = (float*)(ws + o_xs8);
    float* a_d      = (float*)(ws + o_ad);
    float* y        = (float*)(ws + o_y);
    int* bstart     = (int*)(ws + o_bstart);
    float* g2       = (float*)(ws + o_g2);
    uint2* slab     = (uint2*)(ws + o_slab);
    float* partials = (float*)(ws + o_part);

    hipMemsetAsync(d_ws, 0, zero_bytes, stream);

    k_easum_part<<<EPARTS, 256, 0, stream>>>(ea, epart, E);
    k_setup<<<1, 128, 0, stream>>>(W_gat, att_src, att_dst, W_edge, att_edge, b_gat,
                                   W_fc1, b_fc1, epart, consts);

    int nbl = (N + 255) / 256;
    k_nodes<<<nbl, 256, 0, stream>>>(x, consts, xs8, a_d, pool_batch, bstart, N, B);
    k_p1<<<(E + TILE - 1) / TILE, 256, 0, stream>>>(src, dst, ea, consts, slab, gcur, E, R, CAP);
    dim3 g2grid(S, R);
    k_p2<<<g2grid, 256, 0, stream>>>(slab, gcur, xs8, a_d, partials, S, CAP, N);
    k_p3<<<nbl, 256, 0, stream>>>(partials, xs8, a_d, consts, y, N, S, inv_E);
    k_pool<<<2 * B, 128, 0, stream>>>(y, consts, bstart, g2, B, N);
    k_head<<<B, 128, 0, stream>>>(g2, bstart, agent, W_fc2, b_fc2, W_v1, b_v1, W_v2, b_v2,
                                  W_a1, b_a1, W_a2, b_a2, (float*)d_out, A, B);
}